// Round 6
// baseline (345.846 us; speedup 1.0000x reference)
//
#include <hip/hip_runtime.h>
#include <hip/hip_bf16.h>

#define N_NODES 50000
#define N_E0    800000
#define N_ET    850000
#define EPSBN   1e-5f
#define LOG2E   1.4426950408889634f

#define LEAKY(z) fmaxf((z), 0.2f * (z))

// ---- workspace layout (32-bit word offsets) ----
#define OFF_C 0                 // layer1 C bf16-packed (64N words); overlaid by DSTB/SRCB during CSR build; layer2 C f32
#define OFF_A (128*N_NODES)     // xl2b (bf16) / xl3
#define OFF_B (192*N_NODES)     // xr2 (f32) / xr3
#define OFF_STATS (256*N_NODES)
#define OFF_S1R (OFF_STATS + 512)            // 64 replicas x 256
#define OFF_S2R (OFF_S1R + 16384)            // 64 replicas x 128
#define OFF_P (OFF_S2R + 8192)
#define N_PARAM_TOT 118312
#define OFF_ROWPTR (OFF_P + N_PARAM_TOT)      // 50001 ints
#define OFF_DEG    (OFF_ROWPTR + 50001)       // 50000 ints
#define OFF_CURSOR (OFF_DEG + 50000)          // 50000 ints
#define OFF_BSUM   (OFF_CURSOR + 50000)       // 256 ints
#define OFF_COL    (OFF_BSUM + 256)           // 850000 + 64 pad ints
#define OFF_FLAGS  (OFF_COL + 850064)         // 2 ints
#define OFF_SCNT   (OFF_FLAGS + 2)            // 8 stripe cursors

// per-stripe bucket segments, overlaid on the C region (C written later)
#define BK_CAP 131072
#define BK_CHUNK 2048

typedef float v2f __attribute__((ext_vector_type(2)));

__device__ __forceinline__ v2f ld2(const float* p) { return *(const v2f*)p; }
__device__ __forceinline__ v2f fma2(v2f a, v2f b, v2f c) {
    return __builtin_elementwise_fma(a, b, c);
}
__device__ __forceinline__ v2f max2(v2f a, v2f b) {
    return __builtin_elementwise_max(a, b);
}

__device__ __forceinline__ float bf2f(unsigned short u) {
    return __uint_as_float(((unsigned int)u) << 16);
}
__device__ __forceinline__ unsigned short f2bf(float f) {
    unsigned int u = __float_as_uint(f);
    u += 0x7FFFu + ((u >> 16) & 1u);    // round-to-nearest-even
    return (unsigned short)(u >> 16);
}

// ---- prep: dtype detect (block 0) + deg/stats/replica/scnt init + COL pad zero ----
__global__ void prep_kernel(const unsigned short* xr, const int* ei, int* flags,
                            int* deg, float* stats, float* s1r, float* s2r, int* scnt,
                            int* col) {
    int i = blockIdx.x * 256 + threadIdx.x;
    if (i < N_NODES) deg[i] = 0;   // counted in bucket_kernel
    if (i < 512) stats[i] = 0.f;
    if (i < 16384) s1r[i] = 0.f;
    if (i < 8192)  s2r[i] = 0.f;
    if (i < 8) scnt[i] = 0;
    if (i < 64) col[N_ET + i] = 0;  // pad: gather1 dereferences x[col[pad]]
    if (blockIdx.x == 0) {
        __shared__ int c1, c2;
        if (threadIdx.x == 0) { c1 = 0; c2 = 0; }
        __syncthreads();
        int t = threadIdx.x;
        int l1 = 0, l2 = 0;
        for (int k = t; k < 2048; k += 256) {
            float v = bf2f(xr[k]);
            if (!(fabsf(v) <= 100.0f)) l1++;
            if (ei[2 * k + 1] != 0) l2++;
        }
        atomicAdd(&c1, l1);
        atomicAdd(&c2, l2);
        __syncthreads();
        if (t == 0) {
            flags[0] = (c1 > 16) ? 1 : 0;   // 1 => inputs are f32
            flags[1] = (c2 == 0) ? 1 : 0;   // 1 => edge_index is int64
        }
    }
}

struct ParamPtrs { const void* p[23]; };

// stage f32 params; att vectors (t=5,13,21) pre-scaled by log2e so softmax uses exp2
__global__ void convert_kernel(ParamPtrs ps, float* dst, const int* flags) {
    const int sizes[23] = {100000, 256,128,256,128,128,128,128,128,
                           8192,64,8192,64,64,64,64,64,
                           128,2,128,2,2,2};
    int g = blockIdx.x * 256 + threadIdx.x;
    if (g >= N_PARAM_TOT) return;
    int t = 0, off = g;
    while (off >= sizes[t]) { off -= sizes[t]; t++; }
    float v;
    if (flags[0]) v = ((const float*)ps.p[t])[off];
    else          v = bf2f(((const unsigned short*)ps.p[t])[off]);
    if (t == 5 || t == 13 || t == 21) v *= LOG2E;
    dst[g] = v;
}

// ---- pass 1: read edges ONCE; bucket (dst,src) into 8 stripes AND count deg ----
__global__ void bucket_kernel(const int* ei, const int* flags, int* scnt,
                              int* dstb, int* srcb, int* deg) {
    __shared__ int lcnt[8];
    __shared__ int lbase[8];
    int tid = threadIdx.x;
    if (tid < 8) lcnt[tid] = 0;
    __syncthreads();
    int base_e = blockIdx.x * BK_CHUNK;
    int i64 = flags[1];
    int src[8], dst[8], pos[8];
    #pragma unroll
    for (int u = 0; u < 8; u++) {
        int e = base_e + u * 256 + tid;
        if (e < N_ET) {
            int s, d;
            if (e < N_E0) {
                d = i64 ? ei[2 * (N_E0 + e)] : ei[N_E0 + e];
                s = i64 ? ei[2 * e] : ei[e];
            } else { s = d = e - N_E0; }
            src[u] = s; dst[u] = d;
            pos[u] = atomicAdd(&lcnt[d / 6250], 1);
            atomicAdd(&deg[d], 1);           // fused histogram
        } else dst[u] = -1;
    }
    __syncthreads();
    if (tid < 8) lbase[tid] = atomicAdd(&scnt[tid], lcnt[tid]);
    __syncthreads();
    #pragma unroll
    for (int u = 0; u < 8; u++) {
        if (dst[u] >= 0) {
            int st = dst[u] / 6250;
            int gp = st * BK_CAP + lbase[st] + pos[u];
            dstb[gp] = dst[u];
            srcb[gp] = src[u];
        }
    }
}

__global__ void scan1_kernel(const int* deg, int* row_ptr, int* bsum) {
    __shared__ int sh[256];
    int i = blockIdx.x * 256 + threadIdx.x;
    int v = (i < N_NODES) ? deg[i] : 0;
    sh[threadIdx.x] = v;
    __syncthreads();
    for (int off = 1; off < 256; off <<= 1) {
        int t = (threadIdx.x >= off) ? sh[threadIdx.x - off] : 0;
        __syncthreads();
        sh[threadIdx.x] += t;
        __syncthreads();
    }
    if (i < N_NODES) row_ptr[i] = sh[threadIdx.x] - v;
    if (threadIdx.x == 255) bsum[blockIdx.x] = sh[255];
}

__global__ void scan23_kernel(int* row_ptr, int* cursor, const int* bsum) {
    __shared__ int sh[256];
    int t = threadIdx.x;
    int v = (t < 196) ? bsum[t] : 0;
    sh[t] = v;
    __syncthreads();
    for (int off = 1; off < 256; off <<= 1) {
        int u = (t >= off) ? sh[t - off] : 0;
        __syncthreads();
        sh[t] += u;
        __syncthreads();
    }
    int prefix = (blockIdx.x == 0) ? 0 : sh[blockIdx.x - 1];
    int i = blockIdx.x * 256 + t;
    if (i < N_NODES) {
        int r = row_ptr[i] + prefix;
        row_ptr[i] = r;
        cursor[i] = r;
    }
    if (i == 0) row_ptr[N_NODES] = N_ET;
}

// ---- pass 2: striped scatter, reads own segment once; col writes XCD-local ----
__global__ void scatter2_kernel(const int* scnt, const int* dstb, const int* srcb,
                                int* cursor, int* col) {
    int stripe = blockIdx.x & 7;
    int bi = blockIdx.x >> 3;
    int cnt = scnt[stripe];
    int off = stripe * BK_CAP;
    for (int t = bi * 256 + threadIdx.x; t < cnt; t += 32 * 256) {
        int d = dstb[off + t];
        int pos = atomicAdd(&cursor[d], 1);
        col[pos] = srcb[off + t];
    }
}

// ---- layer 1 gather, v6: 4 NODES PER WAVE. v3's proven inner loop, but params
// loaded once per 4 nodes, all 4 first-chunk col+x loads issued up front
// (independent: node1-3 latency hides under node0 compute), and BN stats
// accumulated in registers -> ONE LDS reduce + atomic per 16-node block.
// out[h,c] = (w0[h,c]*S0_h + w1[h,c]*S1_h)/SP_h + bl[h,c] + bias.
__global__ void __launch_bounds__(256) gather1_kernel(
    const int* row_ptr, const int* col, const float* x,
    const float* W1l, const float* b1l, const float* W1r, const float* b1r,
    const float* att, const float* bias, unsigned int* Cb, float* s1r)
{
    int wv = threadIdx.x >> 6;
    int lane = threadIdx.x & 63;
    int n0 = blockIdx.x * 16 + wv * 4;   // 4 nodes/wave, 16/block (50000 = 3125*16)
    int eslot = lane >> 4;     // edge slot in 4-edge batch (0..3)
    int slot  = lane & 15;     // channel slot: 8 ch of head slot>>1
    int c0 = slot << 3;

    // row_ptr[n0..n0+4] via one lane-parallel load
    int rpl = row_ptr[n0 + (lane < 5 ? lane : 4)];
    int r0 = __builtin_amdgcn_readlane(rpl, 0);
    int r1 = __builtin_amdgcn_readlane(rpl, 1);
    int r2 = __builtin_amdgcn_readlane(rpl, 2);
    int r3 = __builtin_amdgcn_readlane(rpl, 3);
    int r4 = __builtin_amdgcn_readlane(rpl, 4);
    int d0 = r1 - r0, d1 = r2 - r1, d2 = r3 - r2, d3 = r4 - r3;

    // prefetch first-chunk col + x for all 4 nodes (independent loads; COL
    // pad zeroed and over-reads land in neighbor rows -> valid node ids)
    int ms0 = col[r0 + lane];
    int ms1 = col[r1 + lane];
    int ms2 = col[r2 + lane];
    int ms3 = col[r3 + lane];
    v2f xs0 = ld2(x + 2 * ms0);
    v2f xs1 = ld2(x + 2 * ms1);
    v2f xs2 = ld2(x + 2 * ms2);
    v2f xs3 = ld2(x + 2 * ms3);

    // persistent per-lane params (loop + epilogue)
    v2f w0[4], w1[4], at[4];
    #pragma unroll
    for (int k = 0; k < 4; k++) {
        w0[k] = ld2(W1l + c0 + 2 * k);
        w1[k] = ld2(W1l + 128 + c0 + 2 * k);
        at[k] = ld2(att + c0 + 2 * k);          // pre-scaled by log2e
    }
    v2f w0o = ld2(W1l + 2 * lane);
    v2f w1o = ld2(W1l + 128 + 2 * lane);
    v2f bo  = ld2(b1l + 2 * lane) + ld2(bias + 2 * lane);

    float bnS0 = 0.f, bnS1 = 0.f, bnQ0 = 0.f, bnQ1 = 0.f;

    auto run_node = [&](int ni, int basei, int degi, v2f xsv) {
        // K = xr(n) + b1l + b1r folded per-node (params from L1)
        v2f xd = ld2(x + 2 * ni);
        v2f xdx = {xd.x, xd.x}, xdy = {xd.y, xd.y};
        v2f K[4];
        #pragma unroll
        for (int k = 0; k < 4; k++) {
            v2f wr0 = ld2(W1r + c0 + 2 * k);
            v2f wr1 = ld2(W1r + 128 + c0 + 2 * k);
            v2f bb  = ld2(b1r + c0 + 2 * k) + ld2(b1l + c0 + 2 * k);
            K[k] = fma2(xdx, wr0, fma2(xdy, wr1, bb));
        }
        float S0 = 0.f, S1 = 0.f, SP = 0.f;
        int cnt = degi < 64 ? degi : 64;
        for (int jb = 0; jb < cnt; jb += 4) {
            int e = jb + eslot;
            float x0s = __shfl(xsv.x, e, 64);
            float x1s = __shfl(xsv.y, e, 64);
            v2f x0 = {x0s, x0s}, x1 = {x1s, x1s};
            v2f lg = {0.f, 0.f};
            #pragma unroll
            for (int k = 0; k < 4; k++) {
                v2f t = fma2(x1, w1[k], fma2(x0, w0[k], K[k]));
                lg = fma2(max2(t, 0.2f * t), at[k], lg);
            }
            float logit = lg.x + lg.y;
            logit += __shfl_xor(logit, 1, 64);   // pair = two slots of one head
            float p = (e < cnt) ? exp2f(logit) : 0.f;
            S0 = fmaf(p, x0s, S0);
            S1 = fmaf(p, x1s, S1);
            SP += p;
        }
        // rare: deg > 64 -> remaining chunks with in-loop loads
        for (int j0 = 64; j0 < degi; j0 += 64) {
            int c2 = degi - j0; if (c2 > 64) c2 = 64;
            int m = col[basei + j0 + lane];
            v2f xv = ld2(x + 2 * m);
            for (int jb = 0; jb < c2; jb += 4) {
                int e = jb + eslot;
                float x0s = __shfl(xv.x, e, 64);
                float x1s = __shfl(xv.y, e, 64);
                v2f x0 = {x0s, x0s}, x1 = {x1s, x1s};
                v2f lg = {0.f, 0.f};
                #pragma unroll
                for (int k = 0; k < 4; k++) {
                    v2f t = fma2(x1, w1[k], fma2(x0, w0[k], K[k]));
                    lg = fma2(max2(t, 0.2f * t), at[k], lg);
                }
                float logit = lg.x + lg.y;
                logit += __shfl_xor(logit, 1, 64);
                float p = (e < c2) ? exp2f(logit) : 0.f;
                S0 = fmaf(p, x0s, S0);
                S1 = fmaf(p, x1s, S1);
                SP += p;
            }
        }
        // reduce over the 4 edge slots (pair lanes already identical)
        #pragma unroll
        for (int m = 16; m <= 32; m <<= 1) {
            S0 += __shfl_xor(S0, m, 64);
            S1 += __shfl_xor(S1, m, 64);
            SP += __shfl_xor(SP, m, 64);
        }
        float inv = 1.f / SP;
        float t0 = S0 * inv, t1 = S1 * inv;
        // lane owns out channels (2*lane, 2*lane+1) of head lane>>3;
        // lane 2*(lane>>3) (slot = 2*head, eslot 0) holds that head's totals
        int hsrc = (lane >> 3) << 1;
        float t0o = __shfl(t0, hsrc, 64);
        float t1o = __shfl(t1, hsrc, 64);
        float ox = fmaf(w0o.x, t0o, fmaf(w1o.x, t1o, bo.x));
        float oy = fmaf(w0o.y, t0o, fmaf(w1o.y, t1o, bo.y));
        Cb[ni * 64 + lane] = ((unsigned int)f2bf(oy) << 16) | f2bf(ox);
        bnS0 += ox; bnS1 += oy;
        bnQ0 += ox * ox; bnQ1 += oy * oy;
    };

    run_node(n0,     r0, d0, xs0);
    run_node(n0 + 1, r1, d1, xs1);
    run_node(n0 + 2, r2, d2, xs2);
    run_node(n0 + 3, r3, d3, xs3);

    // ---- fused BN-stats epilogue (16 nodes per block, ONE reduce+atomic) ----
    __shared__ float sred[4][128];
    __shared__ float qred[4][128];
    sred[wv][2 * lane]     = bnS0;
    sred[wv][2 * lane + 1] = bnS1;
    qred[wv][2 * lane]     = bnQ0;
    qred[wv][2 * lane + 1] = bnQ1;
    __syncthreads();
    int t = threadIdx.x;
    float a;
    if (t < 128) a = sred[0][t] + sred[1][t] + sred[2][t] + sred[3][t];
    else { int c = t - 128; a = qred[0][c] + qred[1][c] + qred[2][c] + qred[3][c]; }
    atomicAdd(&s1r[(blockIdx.x & 63) * 256 + t], a);
}

// ---- replica reduce + BN coefficient finalize (layer 1): single block.
// Writes stats[k]=scale, stats[128+k]=offset so lin2 staging is 1 fma.
__global__ void red1_kernel(const float* s1r, const float* g1, const float* be1,
                            float* stats) {
    __shared__ float ls[256];
    int t = threadIdx.x;
    float a = 0.f;
    for (int r = 0; r < 64; r++) a += s1r[r * 256 + t];
    ls[t] = a;
    __syncthreads();
    if (t < 128) {
        float mu = ls[t] * (1.0f / N_NODES);
        float var = ls[128 + t] * (1.0f / N_NODES) - mu * mu;
        float sc = g1[t] * rsqrtf(var + EPSBN);
        stats[t] = sc;
        stats[128 + t] = be1[t] - mu * sc;
    }
}

// ---- layer 2 linear, v7: 32-node tile (LDS 16.9 KB, grid 1563) for occupancy.
// Register-tiled 2 nodes x 4 ch per thread; fused BN1+ELU on staging (bf16 C in).
// xl2 written as bf16 (gather2's random-gather table); xr2 stays f32.
__global__ void __launch_bounds__(256) lin2_kernel(
    const unsigned int* Cb, const float* stats, const float* Wl, const float* bl,
    const float* Wr, const float* br, unsigned short* xl2b, float* xr2)
{
    __shared__ float h[32 * 132];
    int tid = threadIdx.x;
    int nb = blockIdx.x * 32;
    for (int i = tid; i < 32 * 64; i += 256) {      // uint = 2 bf16 channels
        int ni = i >> 6, kp = i & 63;
        int n = nb + ni;
        int k = 2 * kp;
        float v0 = 0.f, v1 = 0.f;
        if (n < N_NODES) {
            unsigned int pk = Cb[n * 64 + kp];
            float b0 = fmaf(__uint_as_float(pk << 16),        stats[k],     stats[128 + k]);
            float b1 = fmaf(__uint_as_float(pk & 0xffff0000u), stats[k + 1], stats[128 + k + 1]);
            v0 = b0 > 0.f ? b0 : __expf(b0) - 1.f;   // ELU
            v1 = b1 > 0.f ? b1 : __expf(b1) - 1.f;
        }
        h[ni * 132 + k]     = v0;
        h[ni * 132 + k + 1] = v1;
    }
    __syncthreads();
    int kt = (tid & 15) * 4;
    int nt = (tid >> 4) * 2;
    float accl[2][4], accr[2][4];
    #pragma unroll
    for (int i = 0; i < 2; i++) {
        #pragma unroll
        for (int k = 0; k < 4; k++) { accl[i][k] = 0.f; accr[i][k] = 0.f; }
    }
    for (int j = 0; j < 128; j += 4) {
        float4 hv[2];
        #pragma unroll
        for (int i = 0; i < 2; i++)
            hv[i] = *(const float4*)&h[(nt + i) * 132 + j];
        #pragma unroll
        for (int jj = 0; jj < 4; jj++) {
            float4 wl4 = *(const float4*)&Wl[(j + jj) * 64 + kt];
            float4 wr4 = *(const float4*)&Wr[(j + jj) * 64 + kt];
            #pragma unroll
            for (int i = 0; i < 2; i++) {
                float hvv = (jj == 0) ? hv[i].x : (jj == 1) ? hv[i].y :
                            (jj == 2) ? hv[i].z : hv[i].w;
                accl[i][0] += hvv * wl4.x; accl[i][1] += hvv * wl4.y;
                accl[i][2] += hvv * wl4.z; accl[i][3] += hvv * wl4.w;
                accr[i][0] += hvv * wr4.x; accr[i][1] += hvv * wr4.y;
                accr[i][2] += hvv * wr4.z; accr[i][3] += hvv * wr4.w;
            }
        }
    }
    float4 blv = *(const float4*)&bl[kt];
    float4 brv = *(const float4*)&br[kt];
    #pragma unroll
    for (int i = 0; i < 2; i++) {
        int n = nb + nt + i;
        if (n < N_NODES) {
            ushort4 ob;
            ob.x = f2bf(accl[i][0] + blv.x);
            ob.y = f2bf(accl[i][1] + blv.y);
            ob.z = f2bf(accl[i][2] + blv.z);
            ob.w = f2bf(accl[i][3] + blv.w);
            *(ushort4*)&xl2b[n * 64 + kt] = ob;
            float4 o;
            o.x = accr[i][0] + brv.x; o.y = accr[i][1] + brv.y;
            o.z = accr[i][2] + brv.z; o.w = accr[i][3] + brv.w;
            *(float4*)&xr2[n * 64 + kt] = o;
        }
    }
}

// ---- layer 2 gather: 4 edges/wave, 16 lanes/edge, 4 bf16 ch/lane ----
__global__ void __launch_bounds__(256) gather2_kernel(
    const int* row_ptr, const int* col, const unsigned short* xl2b, const float* xr2,
    const float* att, const float* bias, float* C, float* s2r)
{
    int gid = blockIdx.x * 256 + threadIdx.x;
    int n = gid >> 6;
    int lane = threadIdx.x & 63;
    int grp = lane >> 4;       // edge slot (0..3)
    int cidx = lane & 15;      // ch = 4*cidx .. +3
    float4 xrv = *(const float4*)(xr2 + n * 64 + 4 * cidx);
    float4 atv = *(const float4*)(att + 4 * cidx);   // pre-scaled by log2e
    int base = __builtin_amdgcn_readfirstlane(row_ptr[n]);
    int deg  = __builtin_amdgcn_readfirstlane(row_ptr[n + 1]) - base;
    float4 acc = make_float4(0.f, 0.f, 0.f, 0.f);
    float den = 0.f;
    for (int j0 = 0; j0 < deg; j0 += 64) {
        int cnt = deg - j0; if (cnt > 64) cnt = 64;
        int msrc = col[base + j0 + lane];
        for (int j4 = 0; j4 < cnt; j4 += 8) {
            int e0 = j4 + grp, e1 = j4 + 4 + grp;
            int s0 = __shfl(msrc, e0, 64);
            int s1 = __shfl(msrc, e1, 64);
            bool v0 = e0 < cnt, v1 = e1 < cnt;
            s0 = v0 ? s0 : 0;
            s1 = v1 ? s1 : 0;
            uint2 ba = *(const uint2*)(xl2b + (size_t)s0 * 64 + 4 * cidx);
            uint2 bb = *(const uint2*)(xl2b + (size_t)s1 * 64 + 4 * cidx);
            float a0 = __uint_as_float(ba.x << 16);
            float a1 = __uint_as_float(ba.x & 0xffff0000u);
            float a2 = __uint_as_float(ba.y << 16);
            float a3 = __uint_as_float(ba.y & 0xffff0000u);
            float b0 = __uint_as_float(bb.x << 16);
            float b1 = __uint_as_float(bb.x & 0xffff0000u);
            float b2 = __uint_as_float(bb.y << 16);
            float b3 = __uint_as_float(bb.y & 0xffff0000u);
            float pa = LEAKY(a0 + xrv.x) * atv.x;
            pa = fmaf(LEAKY(a1 + xrv.y), atv.y, pa);
            pa = fmaf(LEAKY(a2 + xrv.z), atv.z, pa);
            pa = fmaf(LEAKY(a3 + xrv.w), atv.w, pa);
            float pb = LEAKY(b0 + xrv.x) * atv.x;
            pb = fmaf(LEAKY(b1 + xrv.y), atv.y, pb);
            pb = fmaf(LEAKY(b2 + xrv.z), atv.z, pb);
            pb = fmaf(LEAKY(b3 + xrv.w), atv.w, pb);
            pa += __shfl_xor(pa, 1, 64);    // head = 4 lanes
            pa += __shfl_xor(pa, 2, 64);
            pb += __shfl_xor(pb, 1, 64);
            pb += __shfl_xor(pb, 2, 64);
            float ea = v0 ? exp2f(pa) : 0.f;
            float eb = v1 ? exp2f(pb) : 0.f;
            acc.x = fmaf(ea, a0, acc.x); acc.x = fmaf(eb, b0, acc.x);
            acc.y = fmaf(ea, a1, acc.y); acc.y = fmaf(eb, b1, acc.y);
            acc.z = fmaf(ea, a2, acc.z); acc.z = fmaf(eb, b2, acc.z);
            acc.w = fmaf(ea, a3, acc.w); acc.w = fmaf(eb, b3, acc.w);
            den += ea + eb;
        }
    }
    acc.x += __shfl_xor(acc.x, 16, 64); acc.x += __shfl_xor(acc.x, 32, 64);
    acc.y += __shfl_xor(acc.y, 16, 64); acc.y += __shfl_xor(acc.y, 32, 64);
    acc.z += __shfl_xor(acc.z, 16, 64); acc.z += __shfl_xor(acc.z, 32, 64);
    acc.w += __shfl_xor(acc.w, 16, 64); acc.w += __shfl_xor(acc.w, 32, 64);
    den += __shfl_xor(den, 16, 64);
    den += __shfl_xor(den, 32, 64);
    float inv = 1.f / den;
    float4 bi = *(const float4*)(bias + 4 * cidx);
    float4 o;
    o.x = fmaf(acc.x, inv, bi.x);
    o.y = fmaf(acc.y, inv, bi.y);
    o.z = fmaf(acc.z, inv, bi.z);
    o.w = fmaf(acc.w, inv, bi.w);
    if (lane < 16) *(float4*)(C + n * 64 + 4 * cidx) = o;
    // ---- fused BN-stats epilogue ----
    __shared__ float sred[4][64];
    __shared__ float qred[4][64];
    int wv = threadIdx.x >> 6;
    if (lane < 16) {
        int c = 4 * cidx;
        sred[wv][c]     = o.x; qred[wv][c]     = o.x * o.x;
        sred[wv][c + 1] = o.y; qred[wv][c + 1] = o.y * o.y;
        sred[wv][c + 2] = o.z; qred[wv][c + 2] = o.z * o.z;
        sred[wv][c + 3] = o.w; qred[wv][c + 3] = o.w * o.w;
    }
    __syncthreads();
    int t = threadIdx.x;
    if (t < 128) {
        float a;
        if (t < 64) a = sred[0][t] + sred[1][t] + sred[2][t] + sred[3][t];
        else { int c = t - 64; a = qred[0][c] + qred[1][c] + qred[2][c] + qred[3][c]; }
        atomicAdd(&s2r[(blockIdx.x & 63) * 128 + t], a);
    }
}

// ---- replica reduce + BN coefficient finalize (layer 2): single block ----
__global__ void red2_kernel(const float* s2r, const float* g2, const float* be2,
                            float* stats) {
    __shared__ float ls[128];
    int t = threadIdx.x;   // 128 threads
    float a = 0.f;
    for (int r = 0; r < 64; r++) a += s2r[r * 128 + t];
    ls[t] = a;
    __syncthreads();
    if (t < 64) {
        float mu = ls[t] * (1.0f / N_NODES);
        float var = ls[64 + t] * (1.0f / N_NODES) - mu * mu;
        float sc = g2[t] * rsqrtf(var + EPSBN);
        stats[t] = sc;
        stats[64 + t] = be2[t] - mu * sc;
    }
}

// ---- layer 3 linear: wave/node butterfly reduce, fused BN2+ELU ----
__global__ void __launch_bounds__(256) lin3_kernel(
    const float* C, const float* stats2,
    const float* Wl, const float* bl, const float* Wr, const float* br,
    float* xl3, float* xr3)
{
    int gid = blockIdx.x * 256 + threadIdx.x;
    int n = gid >> 6;
    int lane = threadIdx.x & 63;
    if (n >= N_NODES) return;
    float v = fmaf(C[n * 64 + lane], stats2[lane], stats2[64 + lane]);
    float h = v > 0.f ? v : __expf(v) - 1.f;   // ELU
    float2 wlv = *(const float2*)(Wl + 2 * lane);
    float2 wrv = *(const float2*)(Wr + 2 * lane);
    float a0 = h * wlv.x, a1 = h * wlv.y;
    float r0 = h * wrv.x, r1 = h * wrv.y;
    #pragma unroll
    for (int m = 1; m < 64; m <<= 1) {
        a0 += __shfl_xor(a0, m, 64);
        a1 += __shfl_xor(a1, m, 64);
        r0 += __shfl_xor(r0, m, 64);
        r1 += __shfl_xor(r1, m, 64);
    }
    if (lane == 0) {
        xl3[2 * n]     = a0 + bl[0];
        xl3[2 * n + 1] = a1 + bl[1];
        xr3[2 * n]     = r0 + br[0];
        xr3[2 * n + 1] = r1 + br[1];
    }
}

// ---- layer 3 gather: H=1, C=2; 4 lanes/node, fused output ----
__global__ void __launch_bounds__(256) gather3_kernel(
    const int* row_ptr, const int* col,
    const float* xl3, const float* xr3,
    const float* att, const float* bias,
    void* out, const int* flags) {
    int gid = blockIdx.x * 256 + threadIdx.x;
    int n = gid >> 2;                  // 4 lanes per node
    int q = threadIdx.x & 3;
    if (n >= N_NODES) return;
    float a0 = att[0], a1 = att[1];    // pre-scaled by log2e
    float xr0 = xr3[2 * n], xr1 = xr3[2 * n + 1];
    float acc0 = 0.f, acc1 = 0.f, den = 0.f;
    int e0 = row_ptr[n], e1 = row_ptr[n + 1];
    for (int e = e0 + q; e < e1; e += 4) {
        int src = col[e];
        float2 xs = *(const float2*)(xl3 + 2 * src);
        float z0 = LEAKY(xs.x + xr0);
        float z1 = LEAKY(xs.y + xr1);
        float p = exp2f(fmaf(z0, a0, z1 * a1));
        acc0 = fmaf(p, xs.x, acc0);
        acc1 = fmaf(p, xs.y, acc1);
        den += p;
    }
    acc0 += __shfl_xor(acc0, 1, 64); acc0 += __shfl_xor(acc0, 2, 64);
    acc1 += __shfl_xor(acc1, 1, 64); acc1 += __shfl_xor(acc1, 2, 64);
    den  += __shfl_xor(den, 1, 64);  den  += __shfl_xor(den, 2, 64);
    if (q == 0) {
        float inv = 1.f / den;
        float v0 = fmaf(acc0, inv, bias[0]);
        float v1 = fmaf(acc1, inv, bias[1]);
        if (flags[0]) {
            ((float*)out)[2 * n] = v0;
            ((float*)out)[2 * n + 1] = v1;
        } else {
            ((__hip_bfloat16*)out)[2 * n] = __float2bfloat16(v0);
            ((__hip_bfloat16*)out)[2 * n + 1] = __float2bfloat16(v1);
        }
    }
}

extern "C" void kernel_launch(void* const* d_in, const int* in_sizes, int n_in,
                              void* d_out, int out_size, void* d_ws, size_t ws_size,
                              hipStream_t stream) {
    float* W = (float*)d_ws;
    float* C = W + OFF_C;
    float* A = W + OFF_A;
    float* B = W + OFF_B;
    float* STATS = W + OFF_STATS;
    float* S1R = W + OFF_S1R;
    float* S2R = W + OFF_S2R;
    float* P = W + OFF_P;
    int* ROWPTR = (int*)(W + OFF_ROWPTR);
    int* DEG    = (int*)(W + OFF_DEG);
    int* CURSOR = (int*)(W + OFF_CURSOR);
    int* BSUM   = (int*)(W + OFF_BSUM);
    int* COL    = (int*)(W + OFF_COL);
    int* FLAGS  = (int*)(W + OFF_FLAGS);
    int* SCNT   = (int*)(W + OFF_SCNT);
    // bucket segments overlay the C region (C first written by gather1)
    int* DSTB   = (int*)(W + OFF_C);
    int* SRCB   = DSTB + 8 * BK_CAP;

    const int* ei = (const int*)d_in[1];

    float* Px  = P;
    float* W1l = Px + 100000; float* b1l = W1l + 256; float* W1r = b1l + 128; float* b1r = W1r + 256;
    float* a1  = b1r + 128;   float* bias1 = a1 + 128; float* g1 = bias1 + 128; float* be1 = g1 + 128;
    float* W2l = be1 + 128;   float* b2l = W2l + 8192; float* W2r = b2l + 64;  float* b2r = W2r + 8192;
    float* a2  = b2r + 64;    float* bias2 = a2 + 64;  float* g2 = bias2 + 64; float* be2 = g2 + 64;
    float* W3l = be2 + 64;    float* b3l = W3l + 128;  float* W3r = b3l + 2;   float* b3r = W3r + 128;
    float* a3  = b3r + 2;     float* bias3 = a3 + 2;

    prep_kernel<<<196, 256, 0, stream>>>((const unsigned short*)d_in[0], ei, FLAGS, DEG, STATS, S1R, S2R, SCNT, COL);

    ParamPtrs ps;
    ps.p[0] = d_in[0];
    for (int j = 1; j < 23; j++) ps.p[j] = d_in[j + 1];
    convert_kernel<<<(N_PARAM_TOT + 255) / 256, 256, 0, stream>>>(ps, P, FLAGS);

    // ---- CSR build: read-once bucketing (+fused deg count), then scatter ----
    bucket_kernel<<<(N_ET + BK_CHUNK - 1) / BK_CHUNK, 256, 0, stream>>>(ei, FLAGS, SCNT, DSTB, SRCB, DEG);
    scan1_kernel<<<196, 256, 0, stream>>>(DEG, ROWPTR, BSUM);
    scan23_kernel<<<196, 256, 0, stream>>>(ROWPTR, CURSOR, BSUM);
    scatter2_kernel<<<256, 256, 0, stream>>>(SCNT, DSTB, SRCB, CURSOR, COL);

    // ---- layer 1 (BN stats fused into gather epilogue; bf16 C table) ----
    gather1_kernel<<<N_NODES / 16, 256, 0, stream>>>(ROWPTR, COL, Px, W1l, b1l, W1r, b1r, a1, bias1, (unsigned int*)C, S1R);
    red1_kernel<<<1, 256, 0, stream>>>(S1R, g1, be1, STATS);

    // ---- layer 2 (BN1+ELU via precomputed coeffs; bf16 xl2 table; stats fused) ----
    lin2_kernel<<<(N_NODES + 31) / 32, 256, 0, stream>>>((const unsigned int*)C, STATS, W2l, b2l, W2r, b2r, (unsigned short*)A, B);
    gather2_kernel<<<N_NODES * 64 / 256, 256, 0, stream>>>(ROWPTR, COL, (const unsigned short*)A, B, a2, bias2, C, S2R);
    red2_kernel<<<1, 128, 0, stream>>>(S2R, g2, be2, STATS + 256);

    // ---- layer 3 (BN2+ELU via precomputed coeffs fused into lin3) ----
    lin3_kernel<<<N_NODES * 64 / 256, 256, 0, stream>>>(C, STATS + 256, W3l, b3l, W3r, b3r, A, B);
    gather3_kernel<<<(N_NODES * 4 + 255) / 256, 256, 0, stream>>>(ROWPTR, COL, A, B, a3, bias3, d_out, FLAGS);
}

// Round 7
// 329.267 us; speedup vs baseline: 1.0504x; 1.0504x over previous
//
#include <hip/hip_runtime.h>
#include <hip/hip_bf16.h>

#define N_NODES 50000
#define N_E0    800000
#define N_ET    850000
#define EPSBN   1e-5f
#define LOG2E   1.4426950408889634f

#define LEAKY(z) fmaxf((z), 0.2f * (z))

// ---- workspace layout (32-bit word offsets) ----
#define OFF_C 0                 // layer1 C bf16-packed (64N words); overlaid by DSTB/SRCB during CSR build; layer2 C f32
#define OFF_A (128*N_NODES)     // xl2b (bf16) / xl3
#define OFF_B (192*N_NODES)     // xr2 (f32) / xr3
#define OFF_STATS (256*N_NODES)
#define OFF_S1R (OFF_STATS + 512)            // 64 replicas x 256
#define OFF_S2R (OFF_S1R + 16384)            // 64 replicas x 128
#define OFF_P (OFF_S2R + 8192)
#define N_PARAM_TOT 118312
#define OFF_ROWPTR (OFF_P + N_PARAM_TOT)      // 50001 ints
#define OFF_DEG    (OFF_ROWPTR + 50001)       // 50000 ints
#define OFF_CURSOR (OFF_DEG + 50000)          // 50000 ints
#define OFF_BSUM   (OFF_CURSOR + 50000)       // 256 ints
#define OFF_COL    (OFF_BSUM + 256)           // 850000 + 64 pad ints
#define OFF_FLAGS  (OFF_COL + 850064)         // 2 ints
#define OFF_SCNT   (OFF_FLAGS + 2)            // 8 stripe cursors

// per-stripe bucket segments, overlaid on the C region (C written later)
#define BK_CAP 131072
#define BK_CHUNK 2048

typedef float v2f __attribute__((ext_vector_type(2)));

__device__ __forceinline__ v2f ld2(const float* p) { return *(const v2f*)p; }
__device__ __forceinline__ v2f fma2(v2f a, v2f b, v2f c) {
    return __builtin_elementwise_fma(a, b, c);
}
__device__ __forceinline__ v2f max2(v2f a, v2f b) {
    return __builtin_elementwise_max(a, b);
}

__device__ __forceinline__ float bf2f(unsigned short u) {
    return __uint_as_float(((unsigned int)u) << 16);
}
__device__ __forceinline__ unsigned short f2bf(float f) {
    unsigned int u = __float_as_uint(f);
    u += 0x7FFFu + ((u >> 16) & 1u);    // round-to-nearest-even
    return (unsigned short)(u >> 16);
}

// ---- prep: dtype detect (block 0) + deg/stats/replica/scnt init + COL pad zero ----
__global__ void prep_kernel(const unsigned short* xr, const int* ei, int* flags,
                            int* deg, float* stats, float* s1r, float* s2r, int* scnt,
                            int* col) {
    int i = blockIdx.x * 256 + threadIdx.x;
    if (i < N_NODES) deg[i] = 0;   // counted in bucket_kernel
    if (i < 512) stats[i] = 0.f;
    if (i < 16384) s1r[i] = 0.f;
    if (i < 8192)  s2r[i] = 0.f;
    if (i < 8) scnt[i] = 0;
    if (i < 64) col[N_ET + i] = 0;  // pad: gather1 dereferences x[col[pad]]
    if (blockIdx.x == 0) {
        __shared__ int c1, c2;
        if (threadIdx.x == 0) { c1 = 0; c2 = 0; }
        __syncthreads();
        int t = threadIdx.x;
        int l1 = 0, l2 = 0;
        for (int k = t; k < 2048; k += 256) {
            float v = bf2f(xr[k]);
            if (!(fabsf(v) <= 100.0f)) l1++;
            if (ei[2 * k + 1] != 0) l2++;
        }
        atomicAdd(&c1, l1);
        atomicAdd(&c2, l2);
        __syncthreads();
        if (t == 0) {
            flags[0] = (c1 > 16) ? 1 : 0;   // 1 => inputs are f32
            flags[1] = (c2 == 0) ? 1 : 0;   // 1 => edge_index is int64
        }
    }
}

struct ParamPtrs { const void* p[23]; };

// stage f32 params; att vectors (t=5,13,21) pre-scaled by log2e so softmax uses exp2
__global__ void convert_kernel(ParamPtrs ps, float* dst, const int* flags) {
    const int sizes[23] = {100000, 256,128,256,128,128,128,128,128,
                           8192,64,8192,64,64,64,64,64,
                           128,2,128,2,2,2};
    int g = blockIdx.x * 256 + threadIdx.x;
    if (g >= N_PARAM_TOT) return;
    int t = 0, off = g;
    while (off >= sizes[t]) { off -= sizes[t]; t++; }
    float v;
    if (flags[0]) v = ((const float*)ps.p[t])[off];
    else          v = bf2f(((const unsigned short*)ps.p[t])[off]);
    if (t == 5 || t == 13 || t == 21) v *= LOG2E;
    dst[g] = v;
}

// ---- pass 1: read edges ONCE; bucket (dst,src) into 8 stripes AND count deg ----
__global__ void bucket_kernel(const int* ei, const int* flags, int* scnt,
                              int* dstb, int* srcb, int* deg) {
    __shared__ int lcnt[8];
    __shared__ int lbase[8];
    int tid = threadIdx.x;
    if (tid < 8) lcnt[tid] = 0;
    __syncthreads();
    int base_e = blockIdx.x * BK_CHUNK;
    int i64 = flags[1];
    int src[8], dst[8], pos[8];
    #pragma unroll
    for (int u = 0; u < 8; u++) {
        int e = base_e + u * 256 + tid;
        if (e < N_ET) {
            int s, d;
            if (e < N_E0) {
                d = i64 ? ei[2 * (N_E0 + e)] : ei[N_E0 + e];
                s = i64 ? ei[2 * e] : ei[e];
            } else { s = d = e - N_E0; }
            src[u] = s; dst[u] = d;
            pos[u] = atomicAdd(&lcnt[d / 6250], 1);
            atomicAdd(&deg[d], 1);           // fused histogram
        } else dst[u] = -1;
    }
    __syncthreads();
    if (tid < 8) lbase[tid] = atomicAdd(&scnt[tid], lcnt[tid]);
    __syncthreads();
    #pragma unroll
    for (int u = 0; u < 8; u++) {
        if (dst[u] >= 0) {
            int st = dst[u] / 6250;
            int gp = st * BK_CAP + lbase[st] + pos[u];
            dstb[gp] = dst[u];
            srcb[gp] = src[u];
        }
    }
}

__global__ void scan1_kernel(const int* deg, int* row_ptr, int* bsum) {
    __shared__ int sh[256];
    int i = blockIdx.x * 256 + threadIdx.x;
    int v = (i < N_NODES) ? deg[i] : 0;
    sh[threadIdx.x] = v;
    __syncthreads();
    for (int off = 1; off < 256; off <<= 1) {
        int t = (threadIdx.x >= off) ? sh[threadIdx.x - off] : 0;
        __syncthreads();
        sh[threadIdx.x] += t;
        __syncthreads();
    }
    if (i < N_NODES) row_ptr[i] = sh[threadIdx.x] - v;
    if (threadIdx.x == 255) bsum[blockIdx.x] = sh[255];
}

__global__ void scan23_kernel(int* row_ptr, int* cursor, const int* bsum) {
    __shared__ int sh[256];
    int t = threadIdx.x;
    int v = (t < 196) ? bsum[t] : 0;
    sh[t] = v;
    __syncthreads();
    for (int off = 1; off < 256; off <<= 1) {
        int u = (t >= off) ? sh[t - off] : 0;
        __syncthreads();
        sh[t] += u;
        __syncthreads();
    }
    int prefix = (blockIdx.x == 0) ? 0 : sh[blockIdx.x - 1];
    int i = blockIdx.x * 256 + t;
    if (i < N_NODES) {
        int r = row_ptr[i] + prefix;
        row_ptr[i] = r;
        cursor[i] = r;
    }
    if (i == 0) row_ptr[N_NODES] = N_ET;
}

// ---- pass 2: striped scatter, reads own segment once; col writes XCD-local ----
__global__ void scatter2_kernel(const int* scnt, const int* dstb, const int* srcb,
                                int* cursor, int* col) {
    int stripe = blockIdx.x & 7;
    int bi = blockIdx.x >> 3;
    int cnt = scnt[stripe];
    int off = stripe * BK_CAP;
    for (int t = bi * 256 + threadIdx.x; t < cnt; t += 32 * 256) {
        int d = dstb[off + t];
        int pos = atomicAdd(&cursor[d], 1);
        col[pos] = srcb[off + t];
    }
}

// ---- layer 1 gather, v6: 4 NODES PER WAVE. v3's proven inner loop, but params
// loaded once per 4 nodes, all 4 first-chunk col+x loads issued up front
// (independent: node1-3 latency hides under node0 compute), and BN stats
// accumulated in registers -> ONE LDS reduce + atomic per 16-node block.
// out[h,c] = (w0[h,c]*S0_h + w1[h,c]*S1_h)/SP_h + bl[h,c] + bias.
__global__ void __launch_bounds__(256) gather1_kernel(
    const int* row_ptr, const int* col, const float* x,
    const float* W1l, const float* b1l, const float* W1r, const float* b1r,
    const float* att, const float* bias, unsigned int* Cb, float* s1r)
{
    int wv = threadIdx.x >> 6;
    int lane = threadIdx.x & 63;
    int n0 = blockIdx.x * 16 + wv * 4;   // 4 nodes/wave, 16/block (50000 = 3125*16)
    int eslot = lane >> 4;     // edge slot in 4-edge batch (0..3)
    int slot  = lane & 15;     // channel slot: 8 ch of head slot>>1
    int c0 = slot << 3;

    // row_ptr[n0..n0+4] via one lane-parallel load
    int rpl = row_ptr[n0 + (lane < 5 ? lane : 4)];
    int r0 = __builtin_amdgcn_readlane(rpl, 0);
    int r1 = __builtin_amdgcn_readlane(rpl, 1);
    int r2 = __builtin_amdgcn_readlane(rpl, 2);
    int r3 = __builtin_amdgcn_readlane(rpl, 3);
    int r4 = __builtin_amdgcn_readlane(rpl, 4);
    int d0 = r1 - r0, d1 = r2 - r1, d2 = r3 - r2, d3 = r4 - r3;

    // prefetch first-chunk col + x for all 4 nodes (independent loads; COL
    // pad zeroed and over-reads land in neighbor rows -> valid node ids)
    int ms0 = col[r0 + lane];
    int ms1 = col[r1 + lane];
    int ms2 = col[r2 + lane];
    int ms3 = col[r3 + lane];
    v2f xs0 = ld2(x + 2 * ms0);
    v2f xs1 = ld2(x + 2 * ms1);
    v2f xs2 = ld2(x + 2 * ms2);
    v2f xs3 = ld2(x + 2 * ms3);

    // persistent per-lane params (loop + epilogue)
    v2f w0[4], w1[4], at[4];
    #pragma unroll
    for (int k = 0; k < 4; k++) {
        w0[k] = ld2(W1l + c0 + 2 * k);
        w1[k] = ld2(W1l + 128 + c0 + 2 * k);
        at[k] = ld2(att + c0 + 2 * k);          // pre-scaled by log2e
    }
    v2f w0o = ld2(W1l + 2 * lane);
    v2f w1o = ld2(W1l + 128 + 2 * lane);
    v2f bo  = ld2(b1l + 2 * lane) + ld2(bias + 2 * lane);

    float bnS0 = 0.f, bnS1 = 0.f, bnQ0 = 0.f, bnQ1 = 0.f;

    auto run_node = [&](int ni, int basei, int degi, v2f xsv) {
        // K = xr(n) + b1l + b1r folded per-node (params from L1)
        v2f xd = ld2(x + 2 * ni);
        v2f xdx = {xd.x, xd.x}, xdy = {xd.y, xd.y};
        v2f K[4];
        #pragma unroll
        for (int k = 0; k < 4; k++) {
            v2f wr0 = ld2(W1r + c0 + 2 * k);
            v2f wr1 = ld2(W1r + 128 + c0 + 2 * k);
            v2f bb  = ld2(b1r + c0 + 2 * k) + ld2(b1l + c0 + 2 * k);
            K[k] = fma2(xdx, wr0, fma2(xdy, wr1, bb));
        }
        float S0 = 0.f, S1 = 0.f, SP = 0.f;
        int cnt = degi < 64 ? degi : 64;
        for (int jb = 0; jb < cnt; jb += 4) {
            int e = jb + eslot;
            float x0s = __shfl(xsv.x, e, 64);
            float x1s = __shfl(xsv.y, e, 64);
            v2f x0 = {x0s, x0s}, x1 = {x1s, x1s};
            v2f lg = {0.f, 0.f};
            #pragma unroll
            for (int k = 0; k < 4; k++) {
                v2f t = fma2(x1, w1[k], fma2(x0, w0[k], K[k]));
                lg = fma2(max2(t, 0.2f * t), at[k], lg);
            }
            float logit = lg.x + lg.y;
            logit += __shfl_xor(logit, 1, 64);   // pair = two slots of one head
            float p = (e < cnt) ? exp2f(logit) : 0.f;
            S0 = fmaf(p, x0s, S0);
            S1 = fmaf(p, x1s, S1);
            SP += p;
        }
        // rare: deg > 64 -> remaining chunks with in-loop loads
        for (int j0 = 64; j0 < degi; j0 += 64) {
            int c2 = degi - j0; if (c2 > 64) c2 = 64;
            int m = col[basei + j0 + lane];
            v2f xv = ld2(x + 2 * m);
            for (int jb = 0; jb < c2; jb += 4) {
                int e = jb + eslot;
                float x0s = __shfl(xv.x, e, 64);
                float x1s = __shfl(xv.y, e, 64);
                v2f x0 = {x0s, x0s}, x1 = {x1s, x1s};
                v2f lg = {0.f, 0.f};
                #pragma unroll
                for (int k = 0; k < 4; k++) {
                    v2f t = fma2(x1, w1[k], fma2(x0, w0[k], K[k]));
                    lg = fma2(max2(t, 0.2f * t), at[k], lg);
                }
                float logit = lg.x + lg.y;
                logit += __shfl_xor(logit, 1, 64);
                float p = (e < c2) ? exp2f(logit) : 0.f;
                S0 = fmaf(p, x0s, S0);
                S1 = fmaf(p, x1s, S1);
                SP += p;
            }
        }
        // reduce over the 4 edge slots (pair lanes already identical)
        #pragma unroll
        for (int m = 16; m <= 32; m <<= 1) {
            S0 += __shfl_xor(S0, m, 64);
            S1 += __shfl_xor(S1, m, 64);
            SP += __shfl_xor(SP, m, 64);
        }
        float inv = 1.f / SP;
        float t0 = S0 * inv, t1 = S1 * inv;
        // lane owns out channels (2*lane, 2*lane+1) of head lane>>3;
        // lane 2*(lane>>3) (slot = 2*head, eslot 0) holds that head's totals
        int hsrc = (lane >> 3) << 1;
        float t0o = __shfl(t0, hsrc, 64);
        float t1o = __shfl(t1, hsrc, 64);
        float ox = fmaf(w0o.x, t0o, fmaf(w1o.x, t1o, bo.x));
        float oy = fmaf(w0o.y, t0o, fmaf(w1o.y, t1o, bo.y));
        Cb[ni * 64 + lane] = ((unsigned int)f2bf(oy) << 16) | f2bf(ox);
        bnS0 += ox; bnS1 += oy;
        bnQ0 += ox * ox; bnQ1 += oy * oy;
    };

    run_node(n0,     r0, d0, xs0);
    run_node(n0 + 1, r1, d1, xs1);
    run_node(n0 + 2, r2, d2, xs2);
    run_node(n0 + 3, r3, d3, xs3);

    // ---- fused BN-stats epilogue (16 nodes per block, ONE reduce+atomic) ----
    __shared__ float sred[4][128];
    __shared__ float qred[4][128];
    sred[wv][2 * lane]     = bnS0;
    sred[wv][2 * lane + 1] = bnS1;
    qred[wv][2 * lane]     = bnQ0;
    qred[wv][2 * lane + 1] = bnQ1;
    __syncthreads();
    int t = threadIdx.x;
    float a;
    if (t < 128) a = sred[0][t] + sred[1][t] + sred[2][t] + sred[3][t];
    else { int c = t - 128; a = qred[0][c] + qred[1][c] + qred[2][c] + qred[3][c]; }
    atomicAdd(&s1r[(blockIdx.x & 63) * 256 + t], a);
}

// ---- replica reduce + BN coefficient finalize (layer 1): single block.
// Writes stats[k]=scale, stats[128+k]=offset so lin2 staging is 1 fma.
__global__ void red1_kernel(const float* s1r, const float* g1, const float* be1,
                            float* stats) {
    __shared__ float ls[256];
    int t = threadIdx.x;
    float a = 0.f;
    for (int r = 0; r < 64; r++) a += s1r[r * 256 + t];
    ls[t] = a;
    __syncthreads();
    if (t < 128) {
        float mu = ls[t] * (1.0f / N_NODES);
        float var = ls[128 + t] * (1.0f / N_NODES) - mu * mu;
        float sc = g1[t] * rsqrtf(var + EPSBN);
        stats[t] = sc;
        stats[128 + t] = be1[t] - mu * sc;
    }
}

// ---- layer 2 linear, v8: 64-node tile (v6) + DOUBLE-BUFFERED WEIGHT PREFETCH.
// j-loop unrolled x2: each phase issues next chunk's 8 float4 weight loads,
// then computes current chunk from registers -> L2 latency hidden under FMAs.
// All buffers named + statically indexed (no spill). fused BN1+ELU staging.
__global__ void __launch_bounds__(256) lin2_kernel(
    const unsigned int* Cb, const float* stats, const float* Wl, const float* bl,
    const float* Wr, const float* br, unsigned short* xl2b, float* xr2)
{
    __shared__ float h[64 * 132];
    int tid = threadIdx.x;
    int nb = blockIdx.x * 64;
    for (int i = tid; i < 64 * 64; i += 256) {      // uint = 2 bf16 channels
        int ni = i >> 6, kp = i & 63;
        int n = nb + ni;
        int k = 2 * kp;
        float v0 = 0.f, v1 = 0.f;
        if (n < N_NODES) {
            unsigned int pk = Cb[n * 64 + kp];
            float b0 = fmaf(__uint_as_float(pk << 16),        stats[k],     stats[128 + k]);
            float b1 = fmaf(__uint_as_float(pk & 0xffff0000u), stats[k + 1], stats[128 + k + 1]);
            v0 = b0 > 0.f ? b0 : __expf(b0) - 1.f;   // ELU
            v1 = b1 > 0.f ? b1 : __expf(b1) - 1.f;
        }
        h[ni * 132 + k]     = v0;
        h[ni * 132 + k + 1] = v1;
    }
    __syncthreads();
    int kt = (tid & 15) * 4;
    int nt = (tid >> 4) * 4;
    const float* Wlp = Wl + kt;
    const float* Wrp = Wr + kt;
    float accl[4][4], accr[4][4];
    #pragma unroll
    for (int i = 0; i < 4; i++) {
        #pragma unroll
        for (int k = 0; k < 4; k++) { accl[i][k] = 0.f; accr[i][k] = 0.f; }
    }
    float4 wlA[4], wrA[4], wlB[4], wrB[4];
    #pragma unroll
    for (int jj = 0; jj < 4; jj++) {
        wlA[jj] = *(const float4*)&Wlp[jj * 64];
        wrA[jj] = *(const float4*)&Wrp[jj * 64];
    }
    for (int j = 0; j < 128; j += 8) {
        // ---- phase A: prefetch rows j+4..j+7 into B, compute rows j..j+3 from A
        #pragma unroll
        for (int jj = 0; jj < 4; jj++) {
            wlB[jj] = *(const float4*)&Wlp[(j + 4 + jj) * 64];
            wrB[jj] = *(const float4*)&Wrp[(j + 4 + jj) * 64];
        }
        {
            float4 hv[4];
            #pragma unroll
            for (int i = 0; i < 4; i++)
                hv[i] = *(const float4*)&h[(nt + i) * 132 + j];
            #pragma unroll
            for (int jj = 0; jj < 4; jj++) {
                #pragma unroll
                for (int i = 0; i < 4; i++) {
                    float hvv = (jj == 0) ? hv[i].x : (jj == 1) ? hv[i].y :
                                (jj == 2) ? hv[i].z : hv[i].w;
                    accl[i][0] += hvv * wlA[jj].x; accl[i][1] += hvv * wlA[jj].y;
                    accl[i][2] += hvv * wlA[jj].z; accl[i][3] += hvv * wlA[jj].w;
                    accr[i][0] += hvv * wrA[jj].x; accr[i][1] += hvv * wrA[jj].y;
                    accr[i][2] += hvv * wrA[jj].z; accr[i][3] += hvv * wrA[jj].w;
                }
            }
        }
        // ---- phase B: prefetch rows (j+8)&127.. into A, compute rows j+4..j+7 from B
        int j2 = (j + 8) & 127;   // wrap keeps the dead last prefetch in-bounds
        #pragma unroll
        for (int jj = 0; jj < 4; jj++) {
            wlA[jj] = *(const float4*)&Wlp[(j2 + jj) * 64];
            wrA[jj] = *(const float4*)&Wrp[(j2 + jj) * 64];
        }
        {
            float4 hv[4];
            #pragma unroll
            for (int i = 0; i < 4; i++)
                hv[i] = *(const float4*)&h[(nt + i) * 132 + j + 4];
            #pragma unroll
            for (int jj = 0; jj < 4; jj++) {
                #pragma unroll
                for (int i = 0; i < 4; i++) {
                    float hvv = (jj == 0) ? hv[i].x : (jj == 1) ? hv[i].y :
                                (jj == 2) ? hv[i].z : hv[i].w;
                    accl[i][0] += hvv * wlB[jj].x; accl[i][1] += hvv * wlB[jj].y;
                    accl[i][2] += hvv * wlB[jj].z; accl[i][3] += hvv * wlB[jj].w;
                    accr[i][0] += hvv * wrB[jj].x; accr[i][1] += hvv * wrB[jj].y;
                    accr[i][2] += hvv * wrB[jj].z; accr[i][3] += hvv * wrB[jj].w;
                }
            }
        }
    }
    float4 blv = *(const float4*)&bl[kt];
    float4 brv = *(const float4*)&br[kt];
    #pragma unroll
    for (int i = 0; i < 4; i++) {
        int n = nb + nt + i;
        if (n < N_NODES) {
            ushort4 ob;
            ob.x = f2bf(accl[i][0] + blv.x);
            ob.y = f2bf(accl[i][1] + blv.y);
            ob.z = f2bf(accl[i][2] + blv.z);
            ob.w = f2bf(accl[i][3] + blv.w);
            *(ushort4*)&xl2b[n * 64 + kt] = ob;
            float4 o;
            o.x = accr[i][0] + brv.x; o.y = accr[i][1] + brv.y;
            o.z = accr[i][2] + brv.z; o.w = accr[i][3] + brv.w;
            *(float4*)&xr2[n * 64 + kt] = o;
        }
    }
}

// ---- layer 2 gather: 4 edges/wave, 16 lanes/edge, 4 bf16 ch/lane ----
__global__ void __launch_bounds__(256) gather2_kernel(
    const int* row_ptr, const int* col, const unsigned short* xl2b, const float* xr2,
    const float* att, const float* bias, float* C, float* s2r)
{
    int gid = blockIdx.x * 256 + threadIdx.x;
    int n = gid >> 6;
    int lane = threadIdx.x & 63;
    int grp = lane >> 4;       // edge slot (0..3)
    int cidx = lane & 15;      // ch = 4*cidx .. +3
    float4 xrv = *(const float4*)(xr2 + n * 64 + 4 * cidx);
    float4 atv = *(const float4*)(att + 4 * cidx);   // pre-scaled by log2e
    int base = __builtin_amdgcn_readfirstlane(row_ptr[n]);
    int deg  = __builtin_amdgcn_readfirstlane(row_ptr[n + 1]) - base;
    float4 acc = make_float4(0.f, 0.f, 0.f, 0.f);
    float den = 0.f;
    for (int j0 = 0; j0 < deg; j0 += 64) {
        int cnt = deg - j0; if (cnt > 64) cnt = 64;
        int msrc = col[base + j0 + lane];
        for (int j4 = 0; j4 < cnt; j4 += 8) {
            int e0 = j4 + grp, e1 = j4 + 4 + grp;
            int s0 = __shfl(msrc, e0, 64);
            int s1 = __shfl(msrc, e1, 64);
            bool v0 = e0 < cnt, v1 = e1 < cnt;
            s0 = v0 ? s0 : 0;
            s1 = v1 ? s1 : 0;
            uint2 ba = *(const uint2*)(xl2b + (size_t)s0 * 64 + 4 * cidx);
            uint2 bb = *(const uint2*)(xl2b + (size_t)s1 * 64 + 4 * cidx);
            float a0 = __uint_as_float(ba.x << 16);
            float a1 = __uint_as_float(ba.x & 0xffff0000u);
            float a2 = __uint_as_float(ba.y << 16);
            float a3 = __uint_as_float(ba.y & 0xffff0000u);
            float b0 = __uint_as_float(bb.x << 16);
            float b1 = __uint_as_float(bb.x & 0xffff0000u);
            float b2 = __uint_as_float(bb.y << 16);
            float b3 = __uint_as_float(bb.y & 0xffff0000u);
            float pa = LEAKY(a0 + xrv.x) * atv.x;
            pa = fmaf(LEAKY(a1 + xrv.y), atv.y, pa);
            pa = fmaf(LEAKY(a2 + xrv.z), atv.z, pa);
            pa = fmaf(LEAKY(a3 + xrv.w), atv.w, pa);
            float pb = LEAKY(b0 + xrv.x) * atv.x;
            pb = fmaf(LEAKY(b1 + xrv.y), atv.y, pb);
            pb = fmaf(LEAKY(b2 + xrv.z), atv.z, pb);
            pb = fmaf(LEAKY(b3 + xrv.w), atv.w, pb);
            pa += __shfl_xor(pa, 1, 64);    // head = 4 lanes
            pa += __shfl_xor(pa, 2, 64);
            pb += __shfl_xor(pb, 1, 64);
            pb += __shfl_xor(pb, 2, 64);
            float ea = v0 ? exp2f(pa) : 0.f;
            float eb = v1 ? exp2f(pb) : 0.f;
            acc.x = fmaf(ea, a0, acc.x); acc.x = fmaf(eb, b0, acc.x);
            acc.y = fmaf(ea, a1, acc.y); acc.y = fmaf(eb, b1, acc.y);
            acc.z = fmaf(ea, a2, acc.z); acc.z = fmaf(eb, b2, acc.z);
            acc.w = fmaf(ea, a3, acc.w); acc.w = fmaf(eb, b3, acc.w);
            den += ea + eb;
        }
    }
    acc.x += __shfl_xor(acc.x, 16, 64); acc.x += __shfl_xor(acc.x, 32, 64);
    acc.y += __shfl_xor(acc.y, 16, 64); acc.y += __shfl_xor(acc.y, 32, 64);
    acc.z += __shfl_xor(acc.z, 16, 64); acc.z += __shfl_xor(acc.z, 32, 64);
    acc.w += __shfl_xor(acc.w, 16, 64); acc.w += __shfl_xor(acc.w, 32, 64);
    den += __shfl_xor(den, 16, 64);
    den += __shfl_xor(den, 32, 64);
    float inv = 1.f / den;
    float4 bi = *(const float4*)(bias + 4 * cidx);
    float4 o;
    o.x = fmaf(acc.x, inv, bi.x);
    o.y = fmaf(acc.y, inv, bi.y);
    o.z = fmaf(acc.z, inv, bi.z);
    o.w = fmaf(acc.w, inv, bi.w);
    if (lane < 16) *(float4*)(C + n * 64 + 4 * cidx) = o;
    // ---- fused BN-stats epilogue ----
    __shared__ float sred[4][64];
    __shared__ float qred[4][64];
    int wv = threadIdx.x >> 6;
    if (lane < 16) {
        int c = 4 * cidx;
        sred[wv][c]     = o.x; qred[wv][c]     = o.x * o.x;
        sred[wv][c + 1] = o.y; qred[wv][c + 1] = o.y * o.y;
        sred[wv][c + 2] = o.z; qred[wv][c + 2] = o.z * o.z;
        sred[wv][c + 3] = o.w; qred[wv][c + 3] = o.w * o.w;
    }
    __syncthreads();
    int t = threadIdx.x;
    if (t < 128) {
        float a;
        if (t < 64) a = sred[0][t] + sred[1][t] + sred[2][t] + sred[3][t];
        else { int c = t - 64; a = qred[0][c] + qred[1][c] + qred[2][c] + qred[3][c]; }
        atomicAdd(&s2r[(blockIdx.x & 63) * 128 + t], a);
    }
}

// ---- replica reduce + BN coefficient finalize (layer 2): single block ----
__global__ void red2_kernel(const float* s2r, const float* g2, const float* be2,
                            float* stats) {
    __shared__ float ls[128];
    int t = threadIdx.x;   // 128 threads
    float a = 0.f;
    for (int r = 0; r < 64; r++) a += s2r[r * 128 + t];
    ls[t] = a;
    __syncthreads();
    if (t < 64) {
        float mu = ls[t] * (1.0f / N_NODES);
        float var = ls[64 + t] * (1.0f / N_NODES) - mu * mu;
        float sc = g2[t] * rsqrtf(var + EPSBN);
        stats[t] = sc;
        stats[64 + t] = be2[t] - mu * sc;
    }
}

// ---- layer 3 linear: wave/node butterfly reduce, fused BN2+ELU ----
__global__ void __launch_bounds__(256) lin3_kernel(
    const float* C, const float* stats2,
    const float* Wl, const float* bl, const float* Wr, const float* br,
    float* xl3, float* xr3)
{
    int gid = blockIdx.x * 256 + threadIdx.x;
    int n = gid >> 6;
    int lane = threadIdx.x & 63;
    if (n >= N_NODES) return;
    float v = fmaf(C[n * 64 + lane], stats2[lane], stats2[64 + lane]);
    float h = v > 0.f ? v : __expf(v) - 1.f;   // ELU
    float2 wlv = *(const float2*)(Wl + 2 * lane);
    float2 wrv = *(const float2*)(Wr + 2 * lane);
    float a0 = h * wlv.x, a1 = h * wlv.y;
    float r0 = h * wrv.x, r1 = h * wrv.y;
    #pragma unroll
    for (int m = 1; m < 64; m <<= 1) {
        a0 += __shfl_xor(a0, m, 64);
        a1 += __shfl_xor(a1, m, 64);
        r0 += __shfl_xor(r0, m, 64);
        r1 += __shfl_xor(r1, m, 64);
    }
    if (lane == 0) {
        xl3[2 * n]     = a0 + bl[0];
        xl3[2 * n + 1] = a1 + bl[1];
        xr3[2 * n]     = r0 + br[0];
        xr3[2 * n + 1] = r1 + br[1];
    }
}

// ---- layer 3 gather: H=1, C=2; 4 lanes/node, fused output ----
__global__ void __launch_bounds__(256) gather3_kernel(
    const int* row_ptr, const int* col,
    const float* xl3, const float* xr3,
    const float* att, const float* bias,
    void* out, const int* flags) {
    int gid = blockIdx.x * 256 + threadIdx.x;
    int n = gid >> 2;                  // 4 lanes per node
    int q = threadIdx.x & 3;
    if (n >= N_NODES) return;
    float a0 = att[0], a1 = att[1];    // pre-scaled by log2e
    float xr0 = xr3[2 * n], xr1 = xr3[2 * n + 1];
    float acc0 = 0.f, acc1 = 0.f, den = 0.f;
    int e0 = row_ptr[n], e1 = row_ptr[n + 1];
    for (int e = e0 + q; e < e1; e += 4) {
        int src = col[e];
        float2 xs = *(const float2*)(xl3 + 2 * src);
        float z0 = LEAKY(xs.x + xr0);
        float z1 = LEAKY(xs.y + xr1);
        float p = exp2f(fmaf(z0, a0, z1 * a1));
        acc0 = fmaf(p, xs.x, acc0);
        acc1 = fmaf(p, xs.y, acc1);
        den += p;
    }
    acc0 += __shfl_xor(acc0, 1, 64); acc0 += __shfl_xor(acc0, 2, 64);
    acc1 += __shfl_xor(acc1, 1, 64); acc1 += __shfl_xor(acc1, 2, 64);
    den  += __shfl_xor(den, 1, 64);  den  += __shfl_xor(den, 2, 64);
    if (q == 0) {
        float inv = 1.f / den;
        float v0 = fmaf(acc0, inv, bias[0]);
        float v1 = fmaf(acc1, inv, bias[1]);
        if (flags[0]) {
            ((float*)out)[2 * n] = v0;
            ((float*)out)[2 * n + 1] = v1;
        } else {
            ((__hip_bfloat16*)out)[2 * n] = __float2bfloat16(v0);
            ((__hip_bfloat16*)out)[2 * n + 1] = __float2bfloat16(v1);
        }
    }
}

extern "C" void kernel_launch(void* const* d_in, const int* in_sizes, int n_in,
                              void* d_out, int out_size, void* d_ws, size_t ws_size,
                              hipStream_t stream) {
    float* W = (float*)d_ws;
    float* C = W + OFF_C;
    float* A = W + OFF_A;
    float* B = W + OFF_B;
    float* STATS = W + OFF_STATS;
    float* S1R = W + OFF_S1R;
    float* S2R = W + OFF_S2R;
    float* P = W + OFF_P;
    int* ROWPTR = (int*)(W + OFF_ROWPTR);
    int* DEG    = (int*)(W + OFF_DEG);
    int* CURSOR = (int*)(W + OFF_CURSOR);
    int* BSUM   = (int*)(W + OFF_BSUM);
    int* COL    = (int*)(W + OFF_COL);
    int* FLAGS  = (int*)(W + OFF_FLAGS);
    int* SCNT   = (int*)(W + OFF_SCNT);
    // bucket segments overlay the C region (C first written by gather1)
    int* DSTB   = (int*)(W + OFF_C);
    int* SRCB   = DSTB + 8 * BK_CAP;

    const int* ei = (const int*)d_in[1];

    float* Px  = P;
    float* W1l = Px + 100000; float* b1l = W1l + 256; float* W1r = b1l + 128; float* b1r = W1r + 256;
    float* a1  = b1r + 128;   float* bias1 = a1 + 128; float* g1 = bias1 + 128; float* be1 = g1 + 128;
    float* W2l = be1 + 128;   float* b2l = W2l + 8192; float* W2r = b2l + 64;  float* b2r = W2r + 8192;
    float* a2  = b2r + 64;    float* bias2 = a2 + 64;  float* g2 = bias2 + 64; float* be2 = g2 + 64;
    float* W3l = be2 + 64;    float* b3l = W3l + 128;  float* W3r = b3l + 2;   float* b3r = W3r + 128;
    float* a3  = b3r + 2;     float* bias3 = a3 + 2;

    prep_kernel<<<196, 256, 0, stream>>>((const unsigned short*)d_in[0], ei, FLAGS, DEG, STATS, S1R, S2R, SCNT, COL);

    ParamPtrs ps;
    ps.p[0] = d_in[0];
    for (int j = 1; j < 23; j++) ps.p[j] = d_in[j + 1];
    convert_kernel<<<(N_PARAM_TOT + 255) / 256, 256, 0, stream>>>(ps, P, FLAGS);

    // ---- CSR build: read-once bucketing (+fused deg count), then scatter ----
    bucket_kernel<<<(N_ET + BK_CHUNK - 1) / BK_CHUNK, 256, 0, stream>>>(ei, FLAGS, SCNT, DSTB, SRCB, DEG);
    scan1_kernel<<<196, 256, 0, stream>>>(DEG, ROWPTR, BSUM);
    scan23_kernel<<<196, 256, 0, stream>>>(ROWPTR, CURSOR, BSUM);
    scatter2_kernel<<<256, 256, 0, stream>>>(SCNT, DSTB, SRCB, CURSOR, COL);

    // ---- layer 1 (BN stats fused into gather epilogue; bf16 C table) ----
    gather1_kernel<<<N_NODES / 16, 256, 0, stream>>>(ROWPTR, COL, Px, W1l, b1l, W1r, b1r, a1, bias1, (unsigned int*)C, S1R);
    red1_kernel<<<1, 256, 0, stream>>>(S1R, g1, be1, STATS);

    // ---- layer 2 (BN1+ELU via precomputed coeffs; bf16 xl2 table; stats fused) ----
    lin2_kernel<<<(N_NODES + 63) / 64, 256, 0, stream>>>((const unsigned int*)C, STATS, W2l, b2l, W2r, b2r, (unsigned short*)A, B);
    gather2_kernel<<<N_NODES * 64 / 256, 256, 0, stream>>>(ROWPTR, COL, (const unsigned short*)A, B, a2, bias2, C, S2R);
    red2_kernel<<<1, 128, 0, stream>>>(S2R, g2, be2, STATS + 256);

    // ---- layer 3 (BN2+ELU via precomputed coeffs fused into lin3) ----
    lin3_kernel<<<N_NODES * 64 / 256, 256, 0, stream>>>(C, STATS + 256, W3l, b3l, W3r, b3r, A, B);
    gather3_kernel<<<(N_NODES * 4 + 255) / 256, 256, 0, stream>>>(ROWPTR, COL, A, B, a3, bias3, d_out, FLAGS);
}

// Round 8
// 325.484 us; speedup vs baseline: 1.0626x; 1.0116x over previous
//
#include <hip/hip_runtime.h>
#include <hip/hip_bf16.h>

#define N_NODES 50000
#define N_E0    800000
#define N_ET    850000
#define EPSBN   1e-5f
#define LOG2E   1.4426950408889634f

#define LEAKY(z) fmaxf((z), 0.2f * (z))

// ---- workspace layout (32-bit word offsets) ----
#define OFF_C 0                 // layer1 C bf16-packed (64N words); overlaid by DSTB/SRCB during CSR build; layer2 C f32
#define OFF_A (128*N_NODES)     // xl2b (bf16) / xl3
#define OFF_B (192*N_NODES)     // xr2 (f32) / xr3
#define OFF_STATS (256*N_NODES)
#define OFF_S1R (OFF_STATS + 512)            // 64 replicas x 256
#define OFF_S2R (OFF_S1R + 16384)            // 64 replicas x 128
#define OFF_P (OFF_S2R + 8192)
#define N_PARAM_TOT 118312
#define OFF_ROWPTR (OFF_P + N_PARAM_TOT)      // 50001 ints
#define OFF_DEG    (OFF_ROWPTR + 50001)       // 50000 ints
#define OFF_CURSOR (OFF_DEG + 50000)          // 50000 ints
#define OFF_BSUM   (OFF_CURSOR + 50000)       // 256 ints
#define OFF_COL    (OFF_BSUM + 256)           // 850000 + 64 pad ints
#define OFF_FLAGS  (OFF_COL + 850064)         // 2 ints
#define OFF_SCNT   (OFF_FLAGS + 2)            // 8 stripe cursors

// per-stripe bucket segments, overlaid on the C region (C written later)
#define BK_CAP 131072
#define BK_CHUNK 2048

typedef float v2f __attribute__((ext_vector_type(2)));

__device__ __forceinline__ v2f ld2(const float* p) { return *(const v2f*)p; }
__device__ __forceinline__ v2f fma2(v2f a, v2f b, v2f c) {
    return __builtin_elementwise_fma(a, b, c);
}
__device__ __forceinline__ v2f max2(v2f a, v2f b) {
    return __builtin_elementwise_max(a, b);
}

__device__ __forceinline__ float bf2f(unsigned short u) {
    return __uint_as_float(((unsigned int)u) << 16);
}
__device__ __forceinline__ unsigned short f2bf(float f) {
    unsigned int u = __float_as_uint(f);
    u += 0x7FFFu + ((u >> 16) & 1u);    // round-to-nearest-even
    return (unsigned short)(u >> 16);
}

// ---- prep: dtype detect (block 0) + deg/stats/replica/scnt init + COL pad zero ----
__global__ void prep_kernel(const unsigned short* xr, const int* ei, int* flags,
                            int* deg, float* stats, float* s1r, float* s2r, int* scnt,
                            int* col) {
    int i = blockIdx.x * 256 + threadIdx.x;
    if (i < N_NODES) deg[i] = 0;   // counted in bucket_kernel
    if (i < 512) stats[i] = 0.f;
    if (i < 16384) s1r[i] = 0.f;
    if (i < 8192)  s2r[i] = 0.f;
    if (i < 8) scnt[i] = 0;
    if (i < 64) col[N_ET + i] = 0;  // pad: gather1 dereferences x[col[pad]]
    if (blockIdx.x == 0) {
        __shared__ int c1, c2;
        if (threadIdx.x == 0) { c1 = 0; c2 = 0; }
        __syncthreads();
        int t = threadIdx.x;
        int l1 = 0, l2 = 0;
        for (int k = t; k < 2048; k += 256) {
            float v = bf2f(xr[k]);
            if (!(fabsf(v) <= 100.0f)) l1++;
            if (ei[2 * k + 1] != 0) l2++;
        }
        atomicAdd(&c1, l1);
        atomicAdd(&c2, l2);
        __syncthreads();
        if (t == 0) {
            flags[0] = (c1 > 16) ? 1 : 0;   // 1 => inputs are f32
            flags[1] = (c2 == 0) ? 1 : 0;   // 1 => edge_index is int64
        }
    }
}

struct ParamPtrs { const void* p[23]; };

// stage f32 params; att vectors (t=5,13,21) pre-scaled by log2e so softmax uses exp2
__global__ void convert_kernel(ParamPtrs ps, float* dst, const int* flags) {
    const int sizes[23] = {100000, 256,128,256,128,128,128,128,128,
                           8192,64,8192,64,64,64,64,64,
                           128,2,128,2,2,2};
    int g = blockIdx.x * 256 + threadIdx.x;
    if (g >= N_PARAM_TOT) return;
    int t = 0, off = g;
    while (off >= sizes[t]) { off -= sizes[t]; t++; }
    float v;
    if (flags[0]) v = ((const float*)ps.p[t])[off];
    else          v = bf2f(((const unsigned short*)ps.p[t])[off]);
    if (t == 5 || t == 13 || t == 21) v *= LOG2E;
    dst[g] = v;
}

// ---- pass 1: read edges ONCE; bucket (dst,src) into 8 stripes AND count deg ----
__global__ void bucket_kernel(const int* ei, const int* flags, int* scnt,
                              int* dstb, int* srcb, int* deg) {
    __shared__ int lcnt[8];
    __shared__ int lbase[8];
    int tid = threadIdx.x;
    if (tid < 8) lcnt[tid] = 0;
    __syncthreads();
    int base_e = blockIdx.x * BK_CHUNK;
    int i64 = flags[1];
    int src[8], dst[8], pos[8];
    #pragma unroll
    for (int u = 0; u < 8; u++) {
        int e = base_e + u * 256 + tid;
        if (e < N_ET) {
            int s, d;
            if (e < N_E0) {
                d = i64 ? ei[2 * (N_E0 + e)] : ei[N_E0 + e];
                s = i64 ? ei[2 * e] : ei[e];
            } else { s = d = e - N_E0; }
            src[u] = s; dst[u] = d;
            pos[u] = atomicAdd(&lcnt[d / 6250], 1);
            atomicAdd(&deg[d], 1);           // fused histogram
        } else dst[u] = -1;
    }
    __syncthreads();
    if (tid < 8) lbase[tid] = atomicAdd(&scnt[tid], lcnt[tid]);
    __syncthreads();
    #pragma unroll
    for (int u = 0; u < 8; u++) {
        if (dst[u] >= 0) {
            int st = dst[u] / 6250;
            int gp = st * BK_CAP + lbase[st] + pos[u];
            dstb[gp] = dst[u];
            srcb[gp] = src[u];
        }
    }
}

__global__ void scan1_kernel(const int* deg, int* row_ptr, int* bsum) {
    __shared__ int sh[256];
    int i = blockIdx.x * 256 + threadIdx.x;
    int v = (i < N_NODES) ? deg[i] : 0;
    sh[threadIdx.x] = v;
    __syncthreads();
    for (int off = 1; off < 256; off <<= 1) {
        int t = (threadIdx.x >= off) ? sh[threadIdx.x - off] : 0;
        __syncthreads();
        sh[threadIdx.x] += t;
        __syncthreads();
    }
    if (i < N_NODES) row_ptr[i] = sh[threadIdx.x] - v;
    if (threadIdx.x == 255) bsum[blockIdx.x] = sh[255];
}

__global__ void scan23_kernel(int* row_ptr, int* cursor, const int* bsum) {
    __shared__ int sh[256];
    int t = threadIdx.x;
    int v = (t < 196) ? bsum[t] : 0;
    sh[t] = v;
    __syncthreads();
    for (int off = 1; off < 256; off <<= 1) {
        int u = (t >= off) ? sh[t - off] : 0;
        __syncthreads();
        sh[t] += u;
        __syncthreads();
    }
    int prefix = (blockIdx.x == 0) ? 0 : sh[blockIdx.x - 1];
    int i = blockIdx.x * 256 + t;
    if (i < N_NODES) {
        int r = row_ptr[i] + prefix;
        row_ptr[i] = r;
        cursor[i] = r;
    }
    if (i == 0) row_ptr[N_NODES] = N_ET;
}

// ---- pass 2: striped scatter, reads own segment once; col writes XCD-local ----
__global__ void scatter2_kernel(const int* scnt, const int* dstb, const int* srcb,
                                int* cursor, int* col) {
    int stripe = blockIdx.x & 7;
    int bi = blockIdx.x >> 3;
    int cnt = scnt[stripe];
    int off = stripe * BK_CAP;
    for (int t = bi * 256 + threadIdx.x; t < cnt; t += 32 * 256) {
        int d = dstb[off + t];
        int pos = atomicAdd(&cursor[d], 1);
        col[pos] = srcb[off + t];
    }
}

// ---- layer 1 gather, v6: 4 NODES PER WAVE. v3's proven inner loop, but params
// loaded once per 4 nodes, all 4 first-chunk col+x loads issued up front
// (independent: node1-3 latency hides under node0 compute), and BN stats
// accumulated in registers -> ONE LDS reduce + atomic per 16-node block.
// out[h,c] = (w0[h,c]*S0_h + w1[h,c]*S1_h)/SP_h + bl[h,c] + bias.
__global__ void __launch_bounds__(256) gather1_kernel(
    const int* row_ptr, const int* col, const float* x,
    const float* W1l, const float* b1l, const float* W1r, const float* b1r,
    const float* att, const float* bias, unsigned int* Cb, float* s1r)
{
    int wv = threadIdx.x >> 6;
    int lane = threadIdx.x & 63;
    int n0 = blockIdx.x * 16 + wv * 4;   // 4 nodes/wave, 16/block (50000 = 3125*16)
    int eslot = lane >> 4;     // edge slot in 4-edge batch (0..3)
    int slot  = lane & 15;     // channel slot: 8 ch of head slot>>1
    int c0 = slot << 3;

    // row_ptr[n0..n0+4] via one lane-parallel load
    int rpl = row_ptr[n0 + (lane < 5 ? lane : 4)];
    int r0 = __builtin_amdgcn_readlane(rpl, 0);
    int r1 = __builtin_amdgcn_readlane(rpl, 1);
    int r2 = __builtin_amdgcn_readlane(rpl, 2);
    int r3 = __builtin_amdgcn_readlane(rpl, 3);
    int r4 = __builtin_amdgcn_readlane(rpl, 4);
    int d0 = r1 - r0, d1 = r2 - r1, d2 = r3 - r2, d3 = r4 - r3;

    // prefetch first-chunk col + x for all 4 nodes (independent loads; COL
    // pad zeroed and over-reads land in neighbor rows -> valid node ids)
    int ms0 = col[r0 + lane];
    int ms1 = col[r1 + lane];
    int ms2 = col[r2 + lane];
    int ms3 = col[r3 + lane];
    v2f xs0 = ld2(x + 2 * ms0);
    v2f xs1 = ld2(x + 2 * ms1);
    v2f xs2 = ld2(x + 2 * ms2);
    v2f xs3 = ld2(x + 2 * ms3);

    // persistent per-lane params (loop + epilogue)
    v2f w0[4], w1[4], at[4];
    #pragma unroll
    for (int k = 0; k < 4; k++) {
        w0[k] = ld2(W1l + c0 + 2 * k);
        w1[k] = ld2(W1l + 128 + c0 + 2 * k);
        at[k] = ld2(att + c0 + 2 * k);          // pre-scaled by log2e
    }
    v2f w0o = ld2(W1l + 2 * lane);
    v2f w1o = ld2(W1l + 128 + 2 * lane);
    v2f bo  = ld2(b1l + 2 * lane) + ld2(bias + 2 * lane);

    float bnS0 = 0.f, bnS1 = 0.f, bnQ0 = 0.f, bnQ1 = 0.f;

    auto run_node = [&](int ni, int basei, int degi, v2f xsv) {
        // K = xr(n) + b1l + b1r folded per-node (params from L1)
        v2f xd = ld2(x + 2 * ni);
        v2f xdx = {xd.x, xd.x}, xdy = {xd.y, xd.y};
        v2f K[4];
        #pragma unroll
        for (int k = 0; k < 4; k++) {
            v2f wr0 = ld2(W1r + c0 + 2 * k);
            v2f wr1 = ld2(W1r + 128 + c0 + 2 * k);
            v2f bb  = ld2(b1r + c0 + 2 * k) + ld2(b1l + c0 + 2 * k);
            K[k] = fma2(xdx, wr0, fma2(xdy, wr1, bb));
        }
        float S0 = 0.f, S1 = 0.f, SP = 0.f;
        int cnt = degi < 64 ? degi : 64;
        for (int jb = 0; jb < cnt; jb += 4) {
            int e = jb + eslot;
            float x0s = __shfl(xsv.x, e, 64);
            float x1s = __shfl(xsv.y, e, 64);
            v2f x0 = {x0s, x0s}, x1 = {x1s, x1s};
            v2f lg = {0.f, 0.f};
            #pragma unroll
            for (int k = 0; k < 4; k++) {
                v2f t = fma2(x1, w1[k], fma2(x0, w0[k], K[k]));
                lg = fma2(max2(t, 0.2f * t), at[k], lg);
            }
            float logit = lg.x + lg.y;
            logit += __shfl_xor(logit, 1, 64);   // pair = two slots of one head
            float p = (e < cnt) ? exp2f(logit) : 0.f;
            S0 = fmaf(p, x0s, S0);
            S1 = fmaf(p, x1s, S1);
            SP += p;
        }
        // rare: deg > 64 -> remaining chunks with in-loop loads
        for (int j0 = 64; j0 < degi; j0 += 64) {
            int c2 = degi - j0; if (c2 > 64) c2 = 64;
            int m = col[basei + j0 + lane];
            v2f xv = ld2(x + 2 * m);
            for (int jb = 0; jb < c2; jb += 4) {
                int e = jb + eslot;
                float x0s = __shfl(xv.x, e, 64);
                float x1s = __shfl(xv.y, e, 64);
                v2f x0 = {x0s, x0s}, x1 = {x1s, x1s};
                v2f lg = {0.f, 0.f};
                #pragma unroll
                for (int k = 0; k < 4; k++) {
                    v2f t = fma2(x1, w1[k], fma2(x0, w0[k], K[k]));
                    lg = fma2(max2(t, 0.2f * t), at[k], lg);
                }
                float logit = lg.x + lg.y;
                logit += __shfl_xor(logit, 1, 64);
                float p = (e < c2) ? exp2f(logit) : 0.f;
                S0 = fmaf(p, x0s, S0);
                S1 = fmaf(p, x1s, S1);
                SP += p;
            }
        }
        // reduce over the 4 edge slots (pair lanes already identical)
        #pragma unroll
        for (int m = 16; m <= 32; m <<= 1) {
            S0 += __shfl_xor(S0, m, 64);
            S1 += __shfl_xor(S1, m, 64);
            SP += __shfl_xor(SP, m, 64);
        }
        float inv = 1.f / SP;
        float t0 = S0 * inv, t1 = S1 * inv;
        // lane owns out channels (2*lane, 2*lane+1) of head lane>>3;
        // lane 2*(lane>>3) (slot = 2*head, eslot 0) holds that head's totals
        int hsrc = (lane >> 3) << 1;
        float t0o = __shfl(t0, hsrc, 64);
        float t1o = __shfl(t1, hsrc, 64);
        float ox = fmaf(w0o.x, t0o, fmaf(w1o.x, t1o, bo.x));
        float oy = fmaf(w0o.y, t0o, fmaf(w1o.y, t1o, bo.y));
        Cb[ni * 64 + lane] = ((unsigned int)f2bf(oy) << 16) | f2bf(ox);
        bnS0 += ox; bnS1 += oy;
        bnQ0 += ox * ox; bnQ1 += oy * oy;
    };

    run_node(n0,     r0, d0, xs0);
    run_node(n0 + 1, r1, d1, xs1);
    run_node(n0 + 2, r2, d2, xs2);
    run_node(n0 + 3, r3, d3, xs3);

    // ---- fused BN-stats epilogue (16 nodes per block, ONE reduce+atomic) ----
    __shared__ float sred[4][128];
    __shared__ float qred[4][128];
    sred[wv][2 * lane]     = bnS0;
    sred[wv][2 * lane + 1] = bnS1;
    qred[wv][2 * lane]     = bnQ0;
    qred[wv][2 * lane + 1] = bnQ1;
    __syncthreads();
    int t = threadIdx.x;
    float a;
    if (t < 128) a = sred[0][t] + sred[1][t] + sred[2][t] + sred[3][t];
    else { int c = t - 128; a = qred[0][c] + qred[1][c] + qred[2][c] + qred[3][c]; }
    atomicAdd(&s1r[(blockIdx.x & 63) * 256 + t], a);
}

// ---- replica reduce + BN coefficient finalize (layer 1): single block.
// Writes stats[k]=scale, stats[128+k]=offset so lin2 staging is 1 fma.
__global__ void red1_kernel(const float* s1r, const float* g1, const float* be1,
                            float* stats) {
    __shared__ float ls[256];
    int t = threadIdx.x;
    float a = 0.f;
    for (int r = 0; r < 64; r++) a += s1r[r * 256 + t];
    ls[t] = a;
    __syncthreads();
    if (t < 128) {
        float mu = ls[t] * (1.0f / N_NODES);
        float var = ls[128 + t] * (1.0f / N_NODES) - mu * mu;
        float sc = g1[t] * rsqrtf(var + EPSBN);
        stats[t] = sc;
        stats[128 + t] = be1[t] - mu * sc;
    }
}

// ---- layer 2 linear, v9: N-SPLIT. Each block computes ONE half (xl via W2l, or
// xr via W2r) for 64 nodes: grid 2x782=1564, per-block loads/FMA halved, total
// unchanged (v7's mistake avoided) -> 2x waves to overlap the same L2 latency.
// fused BN1+ELU on staging (bf16 C in); xl half writes bf16, xr half f32.
__global__ void __launch_bounds__(256) lin2_kernel(
    const unsigned int* Cb, const float* stats, const float* Wl, const float* bl,
    const float* Wr, const float* br, unsigned short* xl2b, float* xr2)
{
    __shared__ float h[64 * 132];
    int tid = threadIdx.x;
    int half = blockIdx.x & 1;
    int nb = (blockIdx.x >> 1) * 64;
    for (int i = tid; i < 64 * 64; i += 256) {      // uint = 2 bf16 channels
        int ni = i >> 6, kp = i & 63;
        int n = nb + ni;
        int k = 2 * kp;
        float v0 = 0.f, v1 = 0.f;
        if (n < N_NODES) {
            unsigned int pk = Cb[n * 64 + kp];
            float b0 = fmaf(__uint_as_float(pk << 16),        stats[k],     stats[128 + k]);
            float b1 = fmaf(__uint_as_float(pk & 0xffff0000u), stats[k + 1], stats[128 + k + 1]);
            v0 = b0 > 0.f ? b0 : __expf(b0) - 1.f;   // ELU
            v1 = b1 > 0.f ? b1 : __expf(b1) - 1.f;
        }
        h[ni * 132 + k]     = v0;
        h[ni * 132 + k + 1] = v1;
    }
    __syncthreads();
    int kt = (tid & 15) * 4;
    int nt = (tid >> 4) * 4;
    const float* Wp = half ? (Wr + kt) : (Wl + kt);
    float acc[4][4];
    #pragma unroll
    for (int i = 0; i < 4; i++) {
        #pragma unroll
        for (int k = 0; k < 4; k++) acc[i][k] = 0.f;
    }
    for (int j = 0; j < 128; j += 4) {
        float4 hv[4];
        #pragma unroll
        for (int i = 0; i < 4; i++)
            hv[i] = *(const float4*)&h[(nt + i) * 132 + j];
        #pragma unroll
        for (int jj = 0; jj < 4; jj++) {
            float4 w4 = *(const float4*)&Wp[(j + jj) * 64];
            #pragma unroll
            for (int i = 0; i < 4; i++) {
                float hvv = (jj == 0) ? hv[i].x : (jj == 1) ? hv[i].y :
                            (jj == 2) ? hv[i].z : hv[i].w;
                acc[i][0] += hvv * w4.x; acc[i][1] += hvv * w4.y;
                acc[i][2] += hvv * w4.z; acc[i][3] += hvv * w4.w;
            }
        }
    }
    if (half == 0) {
        float4 blv = *(const float4*)&bl[kt];
        #pragma unroll
        for (int i = 0; i < 4; i++) {
            int n = nb + nt + i;
            if (n < N_NODES) {
                ushort4 ob;
                ob.x = f2bf(acc[i][0] + blv.x);
                ob.y = f2bf(acc[i][1] + blv.y);
                ob.z = f2bf(acc[i][2] + blv.z);
                ob.w = f2bf(acc[i][3] + blv.w);
                *(ushort4*)&xl2b[n * 64 + kt] = ob;
            }
        }
    } else {
        float4 brv = *(const float4*)&br[kt];
        #pragma unroll
        for (int i = 0; i < 4; i++) {
            int n = nb + nt + i;
            if (n < N_NODES) {
                float4 o;
                o.x = acc[i][0] + brv.x; o.y = acc[i][1] + brv.y;
                o.z = acc[i][2] + brv.z; o.w = acc[i][3] + brv.w;
                *(float4*)&xr2[n * 64 + kt] = o;
            }
        }
    }
}

// ---- layer 2 gather: 4 edges/wave, 16 lanes/edge, 4 bf16 ch/lane ----
__global__ void __launch_bounds__(256) gather2_kernel(
    const int* row_ptr, const int* col, const unsigned short* xl2b, const float* xr2,
    const float* att, const float* bias, float* C, float* s2r)
{
    int gid = blockIdx.x * 256 + threadIdx.x;
    int n = gid >> 6;
    int lane = threadIdx.x & 63;
    int grp = lane >> 4;       // edge slot (0..3)
    int cidx = lane & 15;      // ch = 4*cidx .. +3
    float4 xrv = *(const float4*)(xr2 + n * 64 + 4 * cidx);
    float4 atv = *(const float4*)(att + 4 * cidx);   // pre-scaled by log2e
    int base = __builtin_amdgcn_readfirstlane(row_ptr[n]);
    int deg  = __builtin_amdgcn_readfirstlane(row_ptr[n + 1]) - base;
    float4 acc = make_float4(0.f, 0.f, 0.f, 0.f);
    float den = 0.f;
    for (int j0 = 0; j0 < deg; j0 += 64) {
        int cnt = deg - j0; if (cnt > 64) cnt = 64;
        int msrc = col[base + j0 + lane];
        for (int j4 = 0; j4 < cnt; j4 += 8) {
            int e0 = j4 + grp, e1 = j4 + 4 + grp;
            int s0 = __shfl(msrc, e0, 64);
            int s1 = __shfl(msrc, e1, 64);
            bool v0 = e0 < cnt, v1 = e1 < cnt;
            s0 = v0 ? s0 : 0;
            s1 = v1 ? s1 : 0;
            uint2 ba = *(const uint2*)(xl2b + (size_t)s0 * 64 + 4 * cidx);
            uint2 bb = *(const uint2*)(xl2b + (size_t)s1 * 64 + 4 * cidx);
            float a0 = __uint_as_float(ba.x << 16);
            float a1 = __uint_as_float(ba.x & 0xffff0000u);
            float a2 = __uint_as_float(ba.y << 16);
            float a3 = __uint_as_float(ba.y & 0xffff0000u);
            float b0 = __uint_as_float(bb.x << 16);
            float b1 = __uint_as_float(bb.x & 0xffff0000u);
            float b2 = __uint_as_float(bb.y << 16);
            float b3 = __uint_as_float(bb.y & 0xffff0000u);
            float pa = LEAKY(a0 + xrv.x) * atv.x;
            pa = fmaf(LEAKY(a1 + xrv.y), atv.y, pa);
            pa = fmaf(LEAKY(a2 + xrv.z), atv.z, pa);
            pa = fmaf(LEAKY(a3 + xrv.w), atv.w, pa);
            float pb = LEAKY(b0 + xrv.x) * atv.x;
            pb = fmaf(LEAKY(b1 + xrv.y), atv.y, pb);
            pb = fmaf(LEAKY(b2 + xrv.z), atv.z, pb);
            pb = fmaf(LEAKY(b3 + xrv.w), atv.w, pb);
            pa += __shfl_xor(pa, 1, 64);    // head = 4 lanes
            pa += __shfl_xor(pa, 2, 64);
            pb += __shfl_xor(pb, 1, 64);
            pb += __shfl_xor(pb, 2, 64);
            float ea = v0 ? exp2f(pa) : 0.f;
            float eb = v1 ? exp2f(pb) : 0.f;
            acc.x = fmaf(ea, a0, acc.x); acc.x = fmaf(eb, b0, acc.x);
            acc.y = fmaf(ea, a1, acc.y); acc.y = fmaf(eb, b1, acc.y);
            acc.z = fmaf(ea, a2, acc.z); acc.z = fmaf(eb, b2, acc.z);
            acc.w = fmaf(ea, a3, acc.w); acc.w = fmaf(eb, b3, acc.w);
            den += ea + eb;
        }
    }
    acc.x += __shfl_xor(acc.x, 16, 64); acc.x += __shfl_xor(acc.x, 32, 64);
    acc.y += __shfl_xor(acc.y, 16, 64); acc.y += __shfl_xor(acc.y, 32, 64);
    acc.z += __shfl_xor(acc.z, 16, 64); acc.z += __shfl_xor(acc.z, 32, 64);
    acc.w += __shfl_xor(acc.w, 16, 64); acc.w += __shfl_xor(acc.w, 32, 64);
    den += __shfl_xor(den, 16, 64);
    den += __shfl_xor(den, 32, 64);
    float inv = 1.f / den;
    float4 bi = *(const float4*)(bias + 4 * cidx);
    float4 o;
    o.x = fmaf(acc.x, inv, bi.x);
    o.y = fmaf(acc.y, inv, bi.y);
    o.z = fmaf(acc.z, inv, bi.z);
    o.w = fmaf(acc.w, inv, bi.w);
    if (lane < 16) *(float4*)(C + n * 64 + 4 * cidx) = o;
    // ---- fused BN-stats epilogue ----
    __shared__ float sred[4][64];
    __shared__ float qred[4][64];
    int wv = threadIdx.x >> 6;
    if (lane < 16) {
        int c = 4 * cidx;
        sred[wv][c]     = o.x; qred[wv][c]     = o.x * o.x;
        sred[wv][c + 1] = o.y; qred[wv][c + 1] = o.y * o.y;
        sred[wv][c + 2] = o.z; qred[wv][c + 2] = o.z * o.z;
        sred[wv][c + 3] = o.w; qred[wv][c + 3] = o.w * o.w;
    }
    __syncthreads();
    int t = threadIdx.x;
    if (t < 128) {
        float a;
        if (t < 64) a = sred[0][t] + sred[1][t] + sred[2][t] + sred[3][t];
        else { int c = t - 64; a = qred[0][c] + qred[1][c] + qred[2][c] + qred[3][c]; }
        atomicAdd(&s2r[(blockIdx.x & 63) * 128 + t], a);
    }
}

// ---- replica reduce + BN coefficient finalize (layer 2): single block ----
__global__ void red2_kernel(const float* s2r, const float* g2, const float* be2,
                            float* stats) {
    __shared__ float ls[128];
    int t = threadIdx.x;   // 128 threads
    float a = 0.f;
    for (int r = 0; r < 64; r++) a += s2r[r * 128 + t];
    ls[t] = a;
    __syncthreads();
    if (t < 64) {
        float mu = ls[t] * (1.0f / N_NODES);
        float var = ls[64 + t] * (1.0f / N_NODES) - mu * mu;
        float sc = g2[t] * rsqrtf(var + EPSBN);
        stats[t] = sc;
        stats[64 + t] = be2[t] - mu * sc;
    }
}

// ---- layer 3 linear: wave/node butterfly reduce, fused BN2+ELU ----
__global__ void __launch_bounds__(256) lin3_kernel(
    const float* C, const float* stats2,
    const float* Wl, const float* bl, const float* Wr, const float* br,
    float* xl3, float* xr3)
{
    int gid = blockIdx.x * 256 + threadIdx.x;
    int n = gid >> 6;
    int lane = threadIdx.x & 63;
    if (n >= N_NODES) return;
    float v = fmaf(C[n * 64 + lane], stats2[lane], stats2[64 + lane]);
    float h = v > 0.f ? v : __expf(v) - 1.f;   // ELU
    float2 wlv = *(const float2*)(Wl + 2 * lane);
    float2 wrv = *(const float2*)(Wr + 2 * lane);
    float a0 = h * wlv.x, a1 = h * wlv.y;
    float r0 = h * wrv.x, r1 = h * wrv.y;
    #pragma unroll
    for (int m = 1; m < 64; m <<= 1) {
        a0 += __shfl_xor(a0, m, 64);
        a1 += __shfl_xor(a1, m, 64);
        r0 += __shfl_xor(r0, m, 64);
        r1 += __shfl_xor(r1, m, 64);
    }
    if (lane == 0) {
        xl3[2 * n]     = a0 + bl[0];
        xl3[2 * n + 1] = a1 + bl[1];
        xr3[2 * n]     = r0 + br[0];
        xr3[2 * n + 1] = r1 + br[1];
    }
}

// ---- layer 3 gather: H=1, C=2; 4 lanes/node, fused output ----
__global__ void __launch_bounds__(256) gather3_kernel(
    const int* row_ptr, const int* col,
    const float* xl3, const float* xr3,
    const float* att, const float* bias,
    void* out, const int* flags) {
    int gid = blockIdx.x * 256 + threadIdx.x;
    int n = gid >> 2;                  // 4 lanes per node
    int q = threadIdx.x & 3;
    if (n >= N_NODES) return;
    float a0 = att[0], a1 = att[1];    // pre-scaled by log2e
    float xr0 = xr3[2 * n], xr1 = xr3[2 * n + 1];
    float acc0 = 0.f, acc1 = 0.f, den = 0.f;
    int e0 = row_ptr[n], e1 = row_ptr[n + 1];
    for (int e = e0 + q; e < e1; e += 4) {
        int src = col[e];
        float2 xs = *(const float2*)(xl3 + 2 * src);
        float z0 = LEAKY(xs.x + xr0);
        float z1 = LEAKY(xs.y + xr1);
        float p = exp2f(fmaf(z0, a0, z1 * a1));
        acc0 = fmaf(p, xs.x, acc0);
        acc1 = fmaf(p, xs.y, acc1);
        den += p;
    }
    acc0 += __shfl_xor(acc0, 1, 64); acc0 += __shfl_xor(acc0, 2, 64);
    acc1 += __shfl_xor(acc1, 1, 64); acc1 += __shfl_xor(acc1, 2, 64);
    den  += __shfl_xor(den, 1, 64);  den  += __shfl_xor(den, 2, 64);
    if (q == 0) {
        float inv = 1.f / den;
        float v0 = fmaf(acc0, inv, bias[0]);
        float v1 = fmaf(acc1, inv, bias[1]);
        if (flags[0]) {
            ((float*)out)[2 * n] = v0;
            ((float*)out)[2 * n + 1] = v1;
        } else {
            ((__hip_bfloat16*)out)[2 * n] = __float2bfloat16(v0);
            ((__hip_bfloat16*)out)[2 * n + 1] = __float2bfloat16(v1);
        }
    }
}

extern "C" void kernel_launch(void* const* d_in, const int* in_sizes, int n_in,
                              void* d_out, int out_size, void* d_ws, size_t ws_size,
                              hipStream_t stream) {
    float* W = (float*)d_ws;
    float* C = W + OFF_C;
    float* A = W + OFF_A;
    float* B = W + OFF_B;
    float* STATS = W + OFF_STATS;
    float* S1R = W + OFF_S1R;
    float* S2R = W + OFF_S2R;
    float* P = W + OFF_P;
    int* ROWPTR = (int*)(W + OFF_ROWPTR);
    int* DEG    = (int*)(W + OFF_DEG);
    int* CURSOR = (int*)(W + OFF_CURSOR);
    int* BSUM   = (int*)(W + OFF_BSUM);
    int* COL    = (int*)(W + OFF_COL);
    int* FLAGS  = (int*)(W + OFF_FLAGS);
    int* SCNT   = (int*)(W + OFF_SCNT);
    // bucket segments overlay the C region (C first written by gather1)
    int* DSTB   = (int*)(W + OFF_C);
    int* SRCB   = DSTB + 8 * BK_CAP;

    const int* ei = (const int*)d_in[1];

    float* Px  = P;
    float* W1l = Px + 100000; float* b1l = W1l + 256; float* W1r = b1l + 128; float* b1r = W1r + 256;
    float* a1  = b1r + 128;   float* bias1 = a1 + 128; float* g1 = bias1 + 128; float* be1 = g1 + 128;
    float* W2l = be1 + 128;   float* b2l = W2l + 8192; float* W2r = b2l + 64;  float* b2r = W2r + 8192;
    float* a2  = b2r + 64;    float* bias2 = a2 + 64;  float* g2 = bias2 + 64; float* be2 = g2 + 64;
    float* W3l = be2 + 64;    float* b3l = W3l + 128;  float* W3r = b3l + 2;   float* b3r = W3r + 128;
    float* a3  = b3r + 2;     float* bias3 = a3 + 2;

    prep_kernel<<<196, 256, 0, stream>>>((const unsigned short*)d_in[0], ei, FLAGS, DEG, STATS, S1R, S2R, SCNT, COL);

    ParamPtrs ps;
    ps.p[0] = d_in[0];
    for (int j = 1; j < 23; j++) ps.p[j] = d_in[j + 1];
    convert_kernel<<<(N_PARAM_TOT + 255) / 256, 256, 0, stream>>>(ps, P, FLAGS);

    // ---- CSR build: read-once bucketing (+fused deg count), then scatter ----
    bucket_kernel<<<(N_ET + BK_CHUNK - 1) / BK_CHUNK, 256, 0, stream>>>(ei, FLAGS, SCNT, DSTB, SRCB, DEG);
    scan1_kernel<<<196, 256, 0, stream>>>(DEG, ROWPTR, BSUM);
    scan23_kernel<<<196, 256, 0, stream>>>(ROWPTR, CURSOR, BSUM);
    scatter2_kernel<<<256, 256, 0, stream>>>(SCNT, DSTB, SRCB, CURSOR, COL);

    // ---- layer 1 (BN stats fused into gather epilogue; bf16 C table) ----
    gather1_kernel<<<N_NODES / 16, 256, 0, stream>>>(ROWPTR, COL, Px, W1l, b1l, W1r, b1r, a1, bias1, (unsigned int*)C, S1R);
    red1_kernel<<<1, 256, 0, stream>>>(S1R, g1, be1, STATS);

    // ---- layer 2 (N-split lin2: even blocks xl/W2l, odd blocks xr/W2r) ----
    lin2_kernel<<<2 * ((N_NODES + 63) / 64), 256, 0, stream>>>((const unsigned int*)C, STATS, W2l, b2l, W2r, b2r, (unsigned short*)A, B);
    gather2_kernel<<<N_NODES * 64 / 256, 256, 0, stream>>>(ROWPTR, COL, (const unsigned short*)A, B, a2, bias2, C, S2R);
    red2_kernel<<<1, 128, 0, stream>>>(S2R, g2, be2, STATS + 256);

    // ---- layer 3 (BN2+ELU via precomputed coeffs fused into lin3) ----
    lin3_kernel<<<N_NODES * 64 / 256, 256, 0, stream>>>(C, STATS + 256, W3l, b3l, W3r, b3r, A, B);
    gather3_kernel<<<(N_NODES * 4 + 255) / 256, 256, 0, stream>>>(ROWPTR, COL, A, B, a3, bias3, d_out, FLAGS);
}

// Round 9
// 310.815 us; speedup vs baseline: 1.1127x; 1.0472x over previous
//
#include <hip/hip_runtime.h>
#include <hip/hip_bf16.h>

#define N_NODES 50000
#define N_E0    800000
#define N_ET    850000
#define EPSBN   1e-5f
#define LOG2E   1.4426950408889634f

#define LEAKY(z) fmaxf((z), 0.2f * (z))

// ---- workspace layout (32-bit word offsets) ----
#define OFF_C 0                 // layer1 C bf16-packed (64N words); overlaid by DSTB/SRCB during CSR build; layer2 C f32
#define OFF_A (128*N_NODES)     // xl2b (bf16) / xl3
#define OFF_B (192*N_NODES)     // xr2 (f32) / xr3
#define OFF_STATS (256*N_NODES)
#define OFF_S1R (OFF_STATS + 512)            // 64 replicas x 256
#define OFF_S2R (OFF_S1R + 16384)            // 64 replicas x 128
#define OFF_P (OFF_S2R + 8192)
#define N_PARAM_TOT 118312
#define OFF_ROWPTR (OFF_P + N_PARAM_TOT)      // 50001 ints
#define OFF_DEG    (OFF_ROWPTR + 50001)       // 50000 ints
#define OFF_CURSOR (OFF_DEG + 50000)          // 50000 ints
#define OFF_BSUM   (OFF_CURSOR + 50000)       // 256 ints
#define OFF_COL    (OFF_BSUM + 256)           // 850000 + 64 pad ints
#define OFF_FLAGS  (OFF_COL + 850064)         // 2 ints
#define OFF_SCNT   (OFF_FLAGS + 2)            // 8 stripe cursors
#define OFF_WF     (OFF_SCNT + 9)             // 16B-aligned; W2 fragment tables (hi+lo bf16, 16384 words)

// per-stripe bucket segments, overlaid on the C region (C written later)
#define BK_CAP 131072
#define BK_CHUNK 2048

typedef float v2f __attribute__((ext_vector_type(2)));
typedef __bf16 bf16x8 __attribute__((ext_vector_type(8)));
typedef float f32x4 __attribute__((ext_vector_type(4)));

__device__ __forceinline__ v2f ld2(const float* p) { return *(const v2f*)p; }
__device__ __forceinline__ v2f fma2(v2f a, v2f b, v2f c) {
    return __builtin_elementwise_fma(a, b, c);
}
__device__ __forceinline__ v2f max2(v2f a, v2f b) {
    return __builtin_elementwise_max(a, b);
}

__device__ __forceinline__ float bf2f(unsigned short u) {
    return __uint_as_float(((unsigned int)u) << 16);
}
__device__ __forceinline__ unsigned short f2bf(float f) {
    unsigned int u = __float_as_uint(f);
    u += 0x7FFFu + ((u >> 16) & 1u);    // round-to-nearest-even
    return (unsigned short)(u >> 16);
}

// ---- prep: dtype detect (block 0) + deg/stats/replica/scnt init + COL pad zero ----
__global__ void prep_kernel(const unsigned short* xr, const int* ei, int* flags,
                            int* deg, float* stats, float* s1r, float* s2r, int* scnt,
                            int* col) {
    int i = blockIdx.x * 256 + threadIdx.x;
    if (i < N_NODES) deg[i] = 0;   // counted in bucket_kernel
    if (i < 512) stats[i] = 0.f;
    if (i < 16384) s1r[i] = 0.f;
    if (i < 8192)  s2r[i] = 0.f;
    if (i < 8) scnt[i] = 0;
    if (i < 64) col[N_ET + i] = 0;  // pad: gather1 dereferences x[col[pad]]
    if (blockIdx.x == 0) {
        __shared__ int c1, c2;
        if (threadIdx.x == 0) { c1 = 0; c2 = 0; }
        __syncthreads();
        int t = threadIdx.x;
        int l1 = 0, l2 = 0;
        for (int k = t; k < 2048; k += 256) {
            float v = bf2f(xr[k]);
            if (!(fabsf(v) <= 100.0f)) l1++;
            if (ei[2 * k + 1] != 0) l2++;
        }
        atomicAdd(&c1, l1);
        atomicAdd(&c2, l2);
        __syncthreads();
        if (t == 0) {
            flags[0] = (c1 > 16) ? 1 : 0;   // 1 => inputs are f32
            flags[1] = (c2 == 0) ? 1 : 0;   // 1 => edge_index is int64
        }
    }
}

struct ParamPtrs { const void* p[23]; };

// stage f32 params; att vectors (t=5,13,21) pre-scaled by log2e so softmax uses exp2
__global__ void convert_kernel(ParamPtrs ps, float* dst, const int* flags) {
    const int sizes[23] = {100000, 256,128,256,128,128,128,128,128,
                           8192,64,8192,64,64,64,64,64,
                           128,2,128,2,2,2};
    int g = blockIdx.x * 256 + threadIdx.x;
    if (g >= N_PARAM_TOT) return;
    int t = 0, off = g;
    while (off >= sizes[t]) { off -= sizes[t]; t++; }
    float v;
    if (flags[0]) v = ((const float*)ps.p[t])[off];
    else          v = bf2f(((const unsigned short*)ps.p[t])[off]);
    if (t == 5 || t == 13 || t == 21) v *= LOG2E;
    dst[g] = v;
}

// ---- W2 fragment pre-arrange for MFMA lin2: combined [k=128][ch=128] matrix
// (ch 0-63 = W2l, 64-127 = W2r) emitted in B-fragment order as hi/lo bf16 split.
// Frag index: lane l of tile (t,s) holds ch = 16t+(l&15), k = 32s+8*(l>>4)+i.
__global__ void wf_kernel(const float* W2l, const float* W2r,
                          unsigned short* wfh, unsigned short* wfl) {
    int g = blockIdx.x * 256 + threadIdx.x;
    if (g >= 2048) return;
    int ts = g >> 6;          // t*4 + s
    int l  = g & 63;
    int t = ts >> 2, s = ts & 3;
    int k0 = 32 * s + 8 * (l >> 4);
    int c  = 16 * t + (l & 15);
    #pragma unroll
    for (int i = 0; i < 8; i++) {
        float v = (c < 64) ? W2l[(k0 + i) * 64 + c] : W2r[(k0 + i) * 64 + (c - 64)];
        unsigned short hi = f2bf(v);
        wfh[g * 8 + i] = hi;
        wfl[g * 8 + i] = f2bf(v - bf2f(hi));
    }
}

// ---- pass 1: read edges ONCE; bucket (dst,src) into 8 stripes AND count deg ----
__global__ void bucket_kernel(const int* ei, const int* flags, int* scnt,
                              int* dstb, int* srcb, int* deg) {
    __shared__ int lcnt[8];
    __shared__ int lbase[8];
    int tid = threadIdx.x;
    if (tid < 8) lcnt[tid] = 0;
    __syncthreads();
    int base_e = blockIdx.x * BK_CHUNK;
    int i64 = flags[1];
    int src[8], dst[8], pos[8];
    #pragma unroll
    for (int u = 0; u < 8; u++) {
        int e = base_e + u * 256 + tid;
        if (e < N_ET) {
            int s, d;
            if (e < N_E0) {
                d = i64 ? ei[2 * (N_E0 + e)] : ei[N_E0 + e];
                s = i64 ? ei[2 * e] : ei[e];
            } else { s = d = e - N_E0; }
            src[u] = s; dst[u] = d;
            pos[u] = atomicAdd(&lcnt[d / 6250], 1);
            atomicAdd(&deg[d], 1);           // fused histogram
        } else dst[u] = -1;
    }
    __syncthreads();
    if (tid < 8) lbase[tid] = atomicAdd(&scnt[tid], lcnt[tid]);
    __syncthreads();
    #pragma unroll
    for (int u = 0; u < 8; u++) {
        if (dst[u] >= 0) {
            int st = dst[u] / 6250;
            int gp = st * BK_CAP + lbase[st] + pos[u];
            dstb[gp] = dst[u];
            srcb[gp] = src[u];
        }
    }
}

__global__ void scan1_kernel(const int* deg, int* row_ptr, int* bsum) {
    __shared__ int sh[256];
    int i = blockIdx.x * 256 + threadIdx.x;
    int v = (i < N_NODES) ? deg[i] : 0;
    sh[threadIdx.x] = v;
    __syncthreads();
    for (int off = 1; off < 256; off <<= 1) {
        int t = (threadIdx.x >= off) ? sh[threadIdx.x - off] : 0;
        __syncthreads();
        sh[threadIdx.x] += t;
        __syncthreads();
    }
    if (i < N_NODES) row_ptr[i] = sh[threadIdx.x] - v;
    if (threadIdx.x == 255) bsum[blockIdx.x] = sh[255];
}

__global__ void scan23_kernel(int* row_ptr, int* cursor, const int* bsum) {
    __shared__ int sh[256];
    int t = threadIdx.x;
    int v = (t < 196) ? bsum[t] : 0;
    sh[t] = v;
    __syncthreads();
    for (int off = 1; off < 256; off <<= 1) {
        int u = (t >= off) ? sh[t - off] : 0;
        __syncthreads();
        sh[t] += u;
        __syncthreads();
    }
    int prefix = (blockIdx.x == 0) ? 0 : sh[blockIdx.x - 1];
    int i = blockIdx.x * 256 + t;
    if (i < N_NODES) {
        int r = row_ptr[i] + prefix;
        row_ptr[i] = r;
        cursor[i] = r;
    }
    if (i == 0) row_ptr[N_NODES] = N_ET;
}

// ---- pass 2: striped scatter, reads own segment once; col writes XCD-local ----
__global__ void scatter2_kernel(const int* scnt, const int* dstb, const int* srcb,
                                int* cursor, int* col) {
    int stripe = blockIdx.x & 7;
    int bi = blockIdx.x >> 3;
    int cnt = scnt[stripe];
    int off = stripe * BK_CAP;
    for (int t = bi * 256 + threadIdx.x; t < cnt; t += 32 * 256) {
        int d = dstb[off + t];
        int pos = atomicAdd(&cursor[d], 1);
        col[pos] = srcb[off + t];
    }
}

// ---- layer 1 gather, v6: 4 NODES PER WAVE (proven). ----
__global__ void __launch_bounds__(256) gather1_kernel(
    const int* row_ptr, const int* col, const float* x,
    const float* W1l, const float* b1l, const float* W1r, const float* b1r,
    const float* att, const float* bias, unsigned int* Cb, float* s1r)
{
    int wv = threadIdx.x >> 6;
    int lane = threadIdx.x & 63;
    int n0 = blockIdx.x * 16 + wv * 4;   // 4 nodes/wave, 16/block (50000 = 3125*16)
    int eslot = lane >> 4;     // edge slot in 4-edge batch (0..3)
    int slot  = lane & 15;     // channel slot: 8 ch of head slot>>1
    int c0 = slot << 3;

    // row_ptr[n0..n0+4] via one lane-parallel load
    int rpl = row_ptr[n0 + (lane < 5 ? lane : 4)];
    int r0 = __builtin_amdgcn_readlane(rpl, 0);
    int r1 = __builtin_amdgcn_readlane(rpl, 1);
    int r2 = __builtin_amdgcn_readlane(rpl, 2);
    int r3 = __builtin_amdgcn_readlane(rpl, 3);
    int r4 = __builtin_amdgcn_readlane(rpl, 4);
    int d0 = r1 - r0, d1 = r2 - r1, d2 = r3 - r2, d3 = r4 - r3;

    // prefetch first-chunk col + x for all 4 nodes (independent loads; COL
    // pad zeroed and over-reads land in neighbor rows -> valid node ids)
    int ms0 = col[r0 + lane];
    int ms1 = col[r1 + lane];
    int ms2 = col[r2 + lane];
    int ms3 = col[r3 + lane];
    v2f xs0 = ld2(x + 2 * ms0);
    v2f xs1 = ld2(x + 2 * ms1);
    v2f xs2 = ld2(x + 2 * ms2);
    v2f xs3 = ld2(x + 2 * ms3);

    // persistent per-lane params (loop + epilogue)
    v2f w0[4], w1[4], at[4];
    #pragma unroll
    for (int k = 0; k < 4; k++) {
        w0[k] = ld2(W1l + c0 + 2 * k);
        w1[k] = ld2(W1l + 128 + c0 + 2 * k);
        at[k] = ld2(att + c0 + 2 * k);          // pre-scaled by log2e
    }
    v2f w0o = ld2(W1l + 2 * lane);
    v2f w1o = ld2(W1l + 128 + 2 * lane);
    v2f bo  = ld2(b1l + 2 * lane) + ld2(bias + 2 * lane);

    float bnS0 = 0.f, bnS1 = 0.f, bnQ0 = 0.f, bnQ1 = 0.f;

    auto run_node = [&](int ni, int basei, int degi, v2f xsv) {
        // K = xr(n) + b1l + b1r folded per-node (params from L1)
        v2f xd = ld2(x + 2 * ni);
        v2f xdx = {xd.x, xd.x}, xdy = {xd.y, xd.y};
        v2f K[4];
        #pragma unroll
        for (int k = 0; k < 4; k++) {
            v2f wr0 = ld2(W1r + c0 + 2 * k);
            v2f wr1 = ld2(W1r + 128 + c0 + 2 * k);
            v2f bb  = ld2(b1r + c0 + 2 * k) + ld2(b1l + c0 + 2 * k);
            K[k] = fma2(xdx, wr0, fma2(xdy, wr1, bb));
        }
        float S0 = 0.f, S1 = 0.f, SP = 0.f;
        int cnt = degi < 64 ? degi : 64;
        for (int jb = 0; jb < cnt; jb += 4) {
            int e = jb + eslot;
            float x0s = __shfl(xsv.x, e, 64);
            float x1s = __shfl(xsv.y, e, 64);
            v2f x0 = {x0s, x0s}, x1 = {x1s, x1s};
            v2f lg = {0.f, 0.f};
            #pragma unroll
            for (int k = 0; k < 4; k++) {
                v2f t = fma2(x1, w1[k], fma2(x0, w0[k], K[k]));
                lg = fma2(max2(t, 0.2f * t), at[k], lg);
            }
            float logit = lg.x + lg.y;
            logit += __shfl_xor(logit, 1, 64);   // pair = two slots of one head
            float p = (e < cnt) ? exp2f(logit) : 0.f;
            S0 = fmaf(p, x0s, S0);
            S1 = fmaf(p, x1s, S1);
            SP += p;
        }
        // rare: deg > 64 -> remaining chunks with in-loop loads
        for (int j0 = 64; j0 < degi; j0 += 64) {
            int c2 = degi - j0; if (c2 > 64) c2 = 64;
            int m = col[basei + j0 + lane];
            v2f xv = ld2(x + 2 * m);
            for (int jb = 0; jb < c2; jb += 4) {
                int e = jb + eslot;
                float x0s = __shfl(xv.x, e, 64);
                float x1s = __shfl(xv.y, e, 64);
                v2f x0 = {x0s, x0s}, x1 = {x1s, x1s};
                v2f lg = {0.f, 0.f};
                #pragma unroll
                for (int k = 0; k < 4; k++) {
                    v2f t = fma2(x1, w1[k], fma2(x0, w0[k], K[k]));
                    lg = fma2(max2(t, 0.2f * t), at[k], lg);
                }
                float logit = lg.x + lg.y;
                logit += __shfl_xor(logit, 1, 64);
                float p = (e < c2) ? exp2f(logit) : 0.f;
                S0 = fmaf(p, x0s, S0);
                S1 = fmaf(p, x1s, S1);
                SP += p;
            }
        }
        // reduce over the 4 edge slots (pair lanes already identical)
        #pragma unroll
        for (int m = 16; m <= 32; m <<= 1) {
            S0 += __shfl_xor(S0, m, 64);
            S1 += __shfl_xor(S1, m, 64);
            SP += __shfl_xor(SP, m, 64);
        }
        float inv = 1.f / SP;
        float t0 = S0 * inv, t1 = S1 * inv;
        // lane owns out channels (2*lane, 2*lane+1) of head lane>>3;
        // lane 2*(lane>>3) (slot = 2*head, eslot 0) holds that head's totals
        int hsrc = (lane >> 3) << 1;
        float t0o = __shfl(t0, hsrc, 64);
        float t1o = __shfl(t1, hsrc, 64);
        float ox = fmaf(w0o.x, t0o, fmaf(w1o.x, t1o, bo.x));
        float oy = fmaf(w0o.y, t0o, fmaf(w1o.y, t1o, bo.y));
        Cb[ni * 64 + lane] = ((unsigned int)f2bf(oy) << 16) | f2bf(ox);
        bnS0 += ox; bnS1 += oy;
        bnQ0 += ox * ox; bnQ1 += oy * oy;
    };

    run_node(n0,     r0, d0, xs0);
    run_node(n0 + 1, r1, d1, xs1);
    run_node(n0 + 2, r2, d2, xs2);
    run_node(n0 + 3, r3, d3, xs3);

    // ---- fused BN-stats epilogue (16 nodes per block, ONE reduce+atomic) ----
    __shared__ float sred[4][128];
    __shared__ float qred[4][128];
    sred[wv][2 * lane]     = bnS0;
    sred[wv][2 * lane + 1] = bnS1;
    qred[wv][2 * lane]     = bnQ0;
    qred[wv][2 * lane + 1] = bnQ1;
    __syncthreads();
    int t = threadIdx.x;
    float a;
    if (t < 128) a = sred[0][t] + sred[1][t] + sred[2][t] + sred[3][t];
    else { int c = t - 128; a = qred[0][c] + qred[1][c] + qred[2][c] + qred[3][c]; }
    atomicAdd(&s1r[(blockIdx.x & 63) * 256 + t], a);
}

// ---- replica reduce + BN coefficient finalize (layer 1): single block.
// Writes stats[k]=scale, stats[128+k]=offset so lin2 staging is 1 fma.
__global__ void red1_kernel(const float* s1r, const float* g1, const float* be1,
                            float* stats) {
    __shared__ float ls[256];
    int t = threadIdx.x;
    float a = 0.f;
    for (int r = 0; r < 64; r++) a += s1r[r * 256 + t];
    ls[t] = a;
    __syncthreads();
    if (t < 128) {
        float mu = ls[t] * (1.0f / N_NODES);
        float var = ls[128 + t] * (1.0f / N_NODES) - mu * mu;
        float sc = g1[t] * rsqrtf(var + EPSBN);
        stats[t] = sc;
        stats[128 + t] = be1[t] - mu * sc;
    }
}

// ---- layer 2 linear, v10: MFMA GEMM. Per block 64 nodes x 128 out (xl||xr),
// K=128, via mfma_f32_16x16x32_bf16. Split-bf16 (hi+lo) on both operands,
// 3 products (hh+hl+lh) -> fp32-class accuracy. h staged in LDS [64][136 bf16]
// (272B rows: 16B-aligned, conflict-free frag reads); W pre-arranged in
// fragment order by wf_kernel (lane-major 16B coalesced, L2-hot).
// Layout invariance: A and B loaded with the SAME k bijection (32s+8g+i), so
// hardware-internal k-slot permutations cancel; C/D mapping is the verified
// col=lane&15, row=(lane>>4)*4+reg.
__global__ void __launch_bounds__(256) lin2_kernel(
    const unsigned int* Cb, const float* stats,
    const unsigned short* wfh, const unsigned short* wfl,
    const float* bl, const float* br,
    unsigned short* xl2b, float* xr2)
{
    __shared__ __align__(16) unsigned int hA[64 * 68];
    __shared__ __align__(16) unsigned int hL[64 * 68];
    int tid = threadIdx.x;
    int nb = blockIdx.x * 64;
    for (int i = tid; i < 64 * 64; i += 256) {      // uint = 2 bf16 channels
        int ni = i >> 6, kp = i & 63;
        int n = nb + ni;
        int k = 2 * kp;
        float v0 = 0.f, v1 = 0.f;
        if (n < N_NODES) {
            unsigned int pk = Cb[n * 64 + kp];
            float b0 = fmaf(__uint_as_float(pk << 16),        stats[k],     stats[128 + k]);
            float b1 = fmaf(__uint_as_float(pk & 0xffff0000u), stats[k + 1], stats[128 + k + 1]);
            v0 = b0 > 0.f ? b0 : __expf(b0) - 1.f;   // ELU
            v1 = b1 > 0.f ? b1 : __expf(b1) - 1.f;
        }
        unsigned short h0 = f2bf(v0), h1 = f2bf(v1);
        unsigned short l0 = f2bf(v0 - bf2f(h0));
        unsigned short l1 = f2bf(v1 - bf2f(h1));
        hA[ni * 68 + kp] = (unsigned int)h0 | ((unsigned int)h1 << 16);
        hL[ni * 68 + kp] = (unsigned int)l0 | ((unsigned int)l1 << 16);
    }
    __syncthreads();
    int wv = tid >> 6;          // wave = 16-node row strip
    int lane = tid & 63;
    int g = lane >> 4, lrow = lane & 15;
    f32x4 acc[8];
    #pragma unroll
    for (int t = 0; t < 8; t++) acc[t] = (f32x4){0.f, 0.f, 0.f, 0.f};
    #pragma unroll
    for (int s = 0; s < 4; s++) {
        int aoff = (wv * 16 + lrow) * 272 + s * 64 + g * 16;   // bytes
        bf16x8 ah = *(const bf16x8*)((const char*)hA + aoff);
        bf16x8 al = *(const bf16x8*)((const char*)hL + aoff);
        #pragma unroll
        for (int t = 0; t < 8; t++) {
            int bi = ((t * 4 + s) * 64 + lane) * 8;
            bf16x8 bh = *(const bf16x8*)(wfh + bi);
            bf16x8 bo = *(const bf16x8*)(wfl + bi);
            acc[t] = __builtin_amdgcn_mfma_f32_16x16x32_bf16(ah, bh, acc[t], 0, 0, 0);
            acc[t] = __builtin_amdgcn_mfma_f32_16x16x32_bf16(ah, bo, acc[t], 0, 0, 0);
            acc[t] = __builtin_amdgcn_mfma_f32_16x16x32_bf16(al, bh, acc[t], 0, 0, 0);
        }
    }
    // writeout: tiles 0-3 -> xl (bf16 table), 4-7 -> xr (f32)
    #pragma unroll
    for (int t = 0; t < 8; t++) {
        int ch = 16 * t + lrow;
        float bias = (t < 4) ? bl[ch] : br[ch - 64];
        #pragma unroll
        for (int r = 0; r < 4; r++) {
            int node = nb + wv * 16 + g * 4 + r;
            if (node < N_NODES) {
                float v = acc[t][r] + bias;
                if (t < 4) xl2b[node * 64 + ch] = f2bf(v);
                else       xr2[node * 64 + ch - 64] = v;
            }
        }
    }
}

// ---- layer 2 gather: 4 edges/wave, 16 lanes/edge, 4 bf16 ch/lane ----
__global__ void __launch_bounds__(256) gather2_kernel(
    const int* row_ptr, const int* col, const unsigned short* xl2b, const float* xr2,
    const float* att, const float* bias, float* C, float* s2r)
{
    int gid = blockIdx.x * 256 + threadIdx.x;
    int n = gid >> 6;
    int lane = threadIdx.x & 63;
    int grp = lane >> 4;       // edge slot (0..3)
    int cidx = lane & 15;      // ch = 4*cidx .. +3
    float4 xrv = *(const float4*)(xr2 + n * 64 + 4 * cidx);
    float4 atv = *(const float4*)(att + 4 * cidx);   // pre-scaled by log2e
    int base = __builtin_amdgcn_readfirstlane(row_ptr[n]);
    int deg  = __builtin_amdgcn_readfirstlane(row_ptr[n + 1]) - base;
    float4 acc = make_float4(0.f, 0.f, 0.f, 0.f);
    float den = 0.f;
    for (int j0 = 0; j0 < deg; j0 += 64) {
        int cnt = deg - j0; if (cnt > 64) cnt = 64;
        int msrc = col[base + j0 + lane];
        for (int j4 = 0; j4 < cnt; j4 += 8) {
            int e0 = j4 + grp, e1 = j4 + 4 + grp;
            int s0 = __shfl(msrc, e0, 64);
            int s1 = __shfl(msrc, e1, 64);
            bool v0 = e0 < cnt, v1 = e1 < cnt;
            s0 = v0 ? s0 : 0;
            s1 = v1 ? s1 : 0;
            uint2 ba = *(const uint2*)(xl2b + (size_t)s0 * 64 + 4 * cidx);
            uint2 bb = *(const uint2*)(xl2b + (size_t)s1 * 64 + 4 * cidx);
            float a0 = __uint_as_float(ba.x << 16);
            float a1 = __uint_as_float(ba.x & 0xffff0000u);
            float a2 = __uint_as_float(ba.y << 16);
            float a3 = __uint_as_float(ba.y & 0xffff0000u);
            float b0 = __uint_as_float(bb.x << 16);
            float b1 = __uint_as_float(bb.x & 0xffff0000u);
            float b2 = __uint_as_float(bb.y << 16);
            float b3 = __uint_as_float(bb.y & 0xffff0000u);
            float pa = LEAKY(a0 + xrv.x) * atv.x;
            pa = fmaf(LEAKY(a1 + xrv.y), atv.y, pa);
            pa = fmaf(LEAKY(a2 + xrv.z), atv.z, pa);
            pa = fmaf(LEAKY(a3 + xrv.w), atv.w, pa);
            float pb = LEAKY(b0 + xrv.x) * atv.x;
            pb = fmaf(LEAKY(b1 + xrv.y), atv.y, pb);
            pb = fmaf(LEAKY(b2 + xrv.z), atv.z, pb);
            pb = fmaf(LEAKY(b3 + xrv.w), atv.w, pb);
            pa += __shfl_xor(pa, 1, 64);    // head = 4 lanes
            pa += __shfl_xor(pa, 2, 64);
            pb += __shfl_xor(pb, 1, 64);
            pb += __shfl_xor(pb, 2, 64);
            float ea = v0 ? exp2f(pa) : 0.f;
            float eb = v1 ? exp2f(pb) : 0.f;
            acc.x = fmaf(ea, a0, acc.x); acc.x = fmaf(eb, b0, acc.x);
            acc.y = fmaf(ea, a1, acc.y); acc.y = fmaf(eb, b1, acc.y);
            acc.z = fmaf(ea, a2, acc.z); acc.z = fmaf(eb, b2, acc.z);
            acc.w = fmaf(ea, a3, acc.w); acc.w = fmaf(eb, b3, acc.w);
            den += ea + eb;
        }
    }
    acc.x += __shfl_xor(acc.x, 16, 64); acc.x += __shfl_xor(acc.x, 32, 64);
    acc.y += __shfl_xor(acc.y, 16, 64); acc.y += __shfl_xor(acc.y, 32, 64);
    acc.z += __shfl_xor(acc.z, 16, 64); acc.z += __shfl_xor(acc.z, 32, 64);
    acc.w += __shfl_xor(acc.w, 16, 64); acc.w += __shfl_xor(acc.w, 32, 64);
    den += __shfl_xor(den, 16, 64);
    den += __shfl_xor(den, 32, 64);
    float inv = 1.f / den;
    float4 bi = *(const float4*)(bias + 4 * cidx);
    float4 o;
    o.x = fmaf(acc.x, inv, bi.x);
    o.y = fmaf(acc.y, inv, bi.y);
    o.z = fmaf(acc.z, inv, bi.z);
    o.w = fmaf(acc.w, inv, bi.w);
    if (lane < 16) *(float4*)(C + n * 64 + 4 * cidx) = o;
    // ---- fused BN-stats epilogue ----
    __shared__ float sred[4][64];
    __shared__ float qred[4][64];
    int wv = threadIdx.x >> 6;
    if (lane < 16) {
        int c = 4 * cidx;
        sred[wv][c]     = o.x; qred[wv][c]     = o.x * o.x;
        sred[wv][c + 1] = o.y; qred[wv][c + 1] = o.y * o.y;
        sred[wv][c + 2] = o.z; qred[wv][c + 2] = o.z * o.z;
        sred[wv][c + 3] = o.w; qred[wv][c + 3] = o.w * o.w;
    }
    __syncthreads();
    int t = threadIdx.x;
    if (t < 128) {
        float a;
        if (t < 64) a = sred[0][t] + sred[1][t] + sred[2][t] + sred[3][t];
        else { int c = t - 64; a = qred[0][c] + qred[1][c] + qred[2][c] + qred[3][c]; }
        atomicAdd(&s2r[(blockIdx.x & 63) * 128 + t], a);
    }
}

// ---- replica reduce + BN coefficient finalize (layer 2): single block ----
__global__ void red2_kernel(const float* s2r, const float* g2, const float* be2,
                            float* stats) {
    __shared__ float ls[128];
    int t = threadIdx.x;   // 128 threads
    float a = 0.f;
    for (int r = 0; r < 64; r++) a += s2r[r * 128 + t];
    ls[t] = a;
    __syncthreads();
    if (t < 64) {
        float mu = ls[t] * (1.0f / N_NODES);
        float var = ls[64 + t] * (1.0f / N_NODES) - mu * mu;
        float sc = g2[t] * rsqrtf(var + EPSBN);
        stats[t] = sc;
        stats[64 + t] = be2[t] - mu * sc;
    }
}

// ---- layer 3 linear: wave/node butterfly reduce, fused BN2+ELU ----
__global__ void __launch_bounds__(256) lin3_kernel(
    const float* C, const float* stats2,
    const float* Wl, const float* bl, const float* Wr, const float* br,
    float* xl3, float* xr3)
{
    int gid = blockIdx.x * 256 + threadIdx.x;
    int n = gid >> 6;
    int lane = threadIdx.x & 63;
    if (n >= N_NODES) return;
    float v = fmaf(C[n * 64 + lane], stats2[lane], stats2[64 + lane]);
    float h = v > 0.f ? v : __expf(v) - 1.f;   // ELU
    float2 wlv = *(const float2*)(Wl + 2 * lane);
    float2 wrv = *(const float2*)(Wr + 2 * lane);
    float a0 = h * wlv.x, a1 = h * wlv.y;
    float r0 = h * wrv.x, r1 = h * wrv.y;
    #pragma unroll
    for (int m = 1; m < 64; m <<= 1) {
        a0 += __shfl_xor(a0, m, 64);
        a1 += __shfl_xor(a1, m, 64);
        r0 += __shfl_xor(r0, m, 64);
        r1 += __shfl_xor(r1, m, 64);
    }
    if (lane == 0) {
        xl3[2 * n]     = a0 + bl[0];
        xl3[2 * n + 1] = a1 + bl[1];
        xr3[2 * n]     = r0 + br[0];
        xr3[2 * n + 1] = r1 + br[1];
    }
}

// ---- layer 3 gather: H=1, C=2; 4 lanes/node, fused output ----
__global__ void __launch_bounds__(256) gather3_kernel(
    const int* row_ptr, const int* col,
    const float* xl3, const float* xr3,
    const float* att, const float* bias,
    void* out, const int* flags) {
    int gid = blockIdx.x * 256 + threadIdx.x;
    int n = gid >> 2;                  // 4 lanes per node
    int q = threadIdx.x & 3;
    if (n >= N_NODES) return;
    float a0 = att[0], a1 = att[1];    // pre-scaled by log2e
    float xr0 = xr3[2 * n], xr1 = xr3[2 * n + 1];
    float acc0 = 0.f, acc1 = 0.f, den = 0.f;
    int e0 = row_ptr[n], e1 = row_ptr[n + 1];
    for (int e = e0 + q; e < e1; e += 4) {
        int src = col[e];
        float2 xs = *(const float2*)(xl3 + 2 * src);
        float z0 = LEAKY(xs.x + xr0);
        float z1 = LEAKY(xs.y + xr1);
        float p = exp2f(fmaf(z0, a0, z1 * a1));
        acc0 = fmaf(p, xs.x, acc0);
        acc1 = fmaf(p, xs.y, acc1);
        den += p;
    }
    acc0 += __shfl_xor(acc0, 1, 64); acc0 += __shfl_xor(acc0, 2, 64);
    acc1 += __shfl_xor(acc1, 1, 64); acc1 += __shfl_xor(acc1, 2, 64);
    den  += __shfl_xor(den, 1, 64);  den  += __shfl_xor(den, 2, 64);
    if (q == 0) {
        float inv = 1.f / den;
        float v0 = fmaf(acc0, inv, bias[0]);
        float v1 = fmaf(acc1, inv, bias[1]);
        if (flags[0]) {
            ((float*)out)[2 * n] = v0;
            ((float*)out)[2 * n + 1] = v1;
        } else {
            ((__hip_bfloat16*)out)[2 * n] = __float2bfloat16(v0);
            ((__hip_bfloat16*)out)[2 * n + 1] = __float2bfloat16(v1);
        }
    }
}

extern "C" void kernel_launch(void* const* d_in, const int* in_sizes, int n_in,
                              void* d_out, int out_size, void* d_ws, size_t ws_size,
                              hipStream_t stream) {
    float* W = (float*)d_ws;
    float* C = W + OFF_C;
    float* A = W + OFF_A;
    float* B = W + OFF_B;
    float* STATS = W + OFF_STATS;
    float* S1R = W + OFF_S1R;
    float* S2R = W + OFF_S2R;
    float* P = W + OFF_P;
    int* ROWPTR = (int*)(W + OFF_ROWPTR);
    int* DEG    = (int*)(W + OFF_DEG);
    int* CURSOR = (int*)(W + OFF_CURSOR);
    int* BSUM   = (int*)(W + OFF_BSUM);
    int* COL    = (int*)(W + OFF_COL);
    int* FLAGS  = (int*)(W + OFF_FLAGS);
    int* SCNT   = (int*)(W + OFF_SCNT);
    // bucket segments overlay the C region (C first written by gather1)
    int* DSTB   = (int*)(W + OFF_C);
    int* SRCB   = DSTB + 8 * BK_CAP;
    unsigned short* WFH = (unsigned short*)(W + OFF_WF);
    unsigned short* WFL = WFH + 16384;

    const int* ei = (const int*)d_in[1];

    float* Px  = P;
    float* W1l = Px + 100000; float* b1l = W1l + 256; float* W1r = b1l + 128; float* b1r = W1r + 256;
    float* a1  = b1r + 128;   float* bias1 = a1 + 128; float* g1 = bias1 + 128; float* be1 = g1 + 128;
    float* W2l = be1 + 128;   float* b2l = W2l + 8192; float* W2r = b2l + 64;  float* b2r = W2r + 8192;
    float* a2  = b2r + 64;    float* bias2 = a2 + 64;  float* g2 = bias2 + 64; float* be2 = g2 + 64;
    float* W3l = be2 + 64;    float* b3l = W3l + 128;  float* W3r = b3l + 2;   float* b3r = W3r + 128;
    float* a3  = b3r + 2;     float* bias3 = a3 + 2;

    prep_kernel<<<196, 256, 0, stream>>>((const unsigned short*)d_in[0], ei, FLAGS, DEG, STATS, S1R, S2R, SCNT, COL);

    ParamPtrs ps;
    ps.p[0] = d_in[0];
    for (int j = 1; j < 23; j++) ps.p[j] = d_in[j + 1];
    convert_kernel<<<(N_PARAM_TOT + 255) / 256, 256, 0, stream>>>(ps, P, FLAGS);
    wf_kernel<<<8, 256, 0, stream>>>(W2l, W2r, WFH, WFL);

    // ---- CSR build: read-once bucketing (+fused deg count), then scatter ----
    bucket_kernel<<<(N_ET + BK_CHUNK - 1) / BK_CHUNK, 256, 0, stream>>>(ei, FLAGS, SCNT, DSTB, SRCB, DEG);
    scan1_kernel<<<196, 256, 0, stream>>>(DEG, ROWPTR, BSUM);
    scan23_kernel<<<196, 256, 0, stream>>>(ROWPTR, CURSOR, BSUM);
    scatter2_kernel<<<256, 256, 0, stream>>>(SCNT, DSTB, SRCB, CURSOR, COL);

    // ---- layer 1 (BN stats fused into gather epilogue; bf16 C table) ----
    gather1_kernel<<<N_NODES / 16, 256, 0, stream>>>(ROWPTR, COL, Px, W1l, b1l, W1r, b1r, a1, bias1, (unsigned int*)C, S1R);
    red1_kernel<<<1, 256, 0, stream>>>(S1R, g1, be1, STATS);

    // ---- layer 2 (MFMA lin2; BN1+ELU fused into staging; bf16 xl2 table) ----
    lin2_kernel<<<(N_NODES + 63) / 64, 256, 0, stream>>>((const unsigned int*)C, STATS, WFH, WFL, b2l, b2r, (unsigned short*)A, B);
    gather2_kernel<<<N_NODES * 64 / 256, 256, 0, stream>>>(ROWPTR, COL, (const unsigned short*)A, B, a2, bias2, C, S2R);
    red2_kernel<<<1, 128, 0, stream>>>(S2R, g2, be2, STATS + 256);

    // ---- layer 3 (BN2+ELU via precomputed coeffs fused into lin3) ----
    lin3_kernel<<<N_NODES * 64 / 256, 256, 0, stream>>>(C, STATS + 256, W3l, b3l, W3r, b3r, A, B);
    gather3_kernel<<<(N_NODES * 4 + 255) / 256, 256, 0, stream>>>(ROWPTR, COL, A, B, a3, bias3, d_out, FLAGS);
}